// Round 1
// baseline (871.189 us; speedup 1.0000x reference)
//
#include <hip/hip_runtime.h>
#include <cstddef>

#define BB 2
#define NN 1024
#define FF 8
#define HH 64
#define TT 16
#define ER 8192
#define EC 32768
#define EA 4
#define NFD 8192   // N*F
#define BTT 32     // B*T

// ---------------- core register-GEMM helpers ----------------
__device__ __forceinline__ void row_fma(float* acc, float x, const float* __restrict__ w) {
#pragma unroll
  for (int c = 0; c < 64; ++c) acc[c] += x * w[c];
}

// acc[0..63] += row[0..63] @ W[64x64] ; W row-major, wave-uniform reads -> s_load
__device__ __forceinline__ void stream_gemm64(float* acc, const float* __restrict__ row,
                                              const float* __restrict__ W) {
  const float4* r4 = (const float4*)row;
  for (int q = 0; q < 16; ++q) {
    float4 v = r4[q];
    const float* w = W + q * 256;
    row_fma(acc, v.x, w);
    row_fma(acc, v.y, w + 64);
    row_fma(acc, v.z, w + 128);
    row_fma(acc, v.w, w + 192);
  }
}

// ---------------- edge prep ----------------
__global__ void k_prep_edges(const float* __restrict__ attr, const float* __restrict__ cw,
                             const float* __restrict__ reW, const float* __restrict__ reB,
                             const float* __restrict__ rgate, const float* __restrict__ cgate,
                             float* __restrict__ mw_r, float* __restrict__ mw_c,
                             int* __restrict__ rcnt, int* __restrict__ ccnt) {
  int i = blockIdx.x * 256 + threadIdx.x;
  if (i < EC) {
    float g = 1.f / (1.f + expf(-cgate[0]));
    mw_c[i] = fminf(fmaxf(g * cw[i], 0.f), 1.f);
  }
  if (i < ER) {
    float ew = reB[0];
#pragma unroll
    for (int a = 0; a < EA; ++a) ew += attr[i * EA + a] * reW[a];
    float g = 1.f / (1.f + expf(-rgate[0]));
    mw_r[i] = fminf(fmaxf(g * ew, 0.f), 1.f);
  }
  if (i < NN) rcnt[i] = 0;
  if (i < NFD) ccnt[i] = 0;
}

// ---------------- fused-weight precompute ----------------
// Wf[k][j] = sum_m lin_W[k][m] * upd_W[m][j]   (upd_W top half)
// v[j]     = sum_m lin_b[m]    * upd_W[m][j]
// Wg[kk*64+i][c] = sum_o W_tc[o*192+i*3+kk] * f1_W[o*64+c]
// cvec[c]  = f1_b[c] + sum_o b_tc[o] * f1_W[o*64+c]
__global__ void k_prep_w(const float* __restrict__ r_lin_W, const float* __restrict__ r_upd_W,
                         const float* __restrict__ r_lin_b,
                         const float* __restrict__ c_lin_W, const float* __restrict__ c_upd_W,
                         const float* __restrict__ c_lin_b,
                         const float* __restrict__ W_tc, const float* __restrict__ b_tc,
                         const float* __restrict__ f1_W, const float* __restrict__ f1_b,
                         float* __restrict__ Wfr, float* __restrict__ v_r,
                         float* __restrict__ Wfc, float* __restrict__ v_c,
                         float* __restrict__ Wg, float* __restrict__ cvec) {
  int tid = threadIdx.x;
  if (blockIdx.x == 0) {
    for (int idx = tid; idx < 4096; idx += 256) {
      int k = idx >> 6, j = idx & 63;
      float s = 0.f;
      for (int m = 0; m < 64; ++m) s += r_lin_W[k * 64 + m] * r_upd_W[m * 64 + j];
      Wfr[idx] = s;
    }
    if (tid < 64) {
      float s = 0.f;
      for (int m = 0; m < 64; ++m) s += r_lin_b[m] * r_upd_W[m * 64 + tid];
      v_r[tid] = s;
    }
  } else if (blockIdx.x == 1) {
    for (int idx = tid; idx < 4096; idx += 256) {
      int k = idx >> 6, j = idx & 63;
      float s = 0.f;
      for (int m = 0; m < 64; ++m) s += c_lin_W[k * 64 + m] * c_upd_W[m * 64 + j];
      Wfc[idx] = s;
    }
    if (tid < 64) {
      float s = 0.f;
      for (int m = 0; m < 64; ++m) s += c_lin_b[m] * c_upd_W[m * 64 + tid];
      v_c[tid] = s;
    }
  } else {
    for (int idx = tid; idx < 12288; idx += 256) {
      int r = idx >> 6, c = idx & 63;
      int kk = r >> 6, i = r & 63;
      float s = 0.f;
      for (int o = 0; o < 64; ++o) s += W_tc[o * 192 + i * 3 + kk] * f1_W[o * 64 + c];
      Wg[idx] = s;
    }
    if (tid < 64) {
      float s = f1_b[tid];
      for (int o = 0; o < 64; ++o) s += b_tc[o] * f1_W[o * 64 + tid];
      cvec[tid] = s;
    }
  }
}

// ---------------- CSR build ----------------
__global__ void k_count(const int* __restrict__ ridx, const int* __restrict__ cidx,
                        int* __restrict__ rcnt, int* __restrict__ ccnt) {
  int e = blockIdx.x * 256 + threadIdx.x;
  if (e < ER) atomicAdd(&rcnt[ridx[ER + e]], 1);
  if (e < EC) atomicAdd(&ccnt[cidx[EC + e]], 1);
}

template <int ITEMS>
__device__ __forceinline__ void scan_impl(const int* __restrict__ cnt, int n,
                                          int* __restrict__ off, int* __restrict__ cur,
                                          int* sh) {
  int tid = threadIdx.x;
  int local[ITEMS];
  int s = 0;
  int base = tid * ITEMS;
#pragma unroll
  for (int j = 0; j < ITEMS; ++j) { local[j] = cnt[base + j]; s += local[j]; }
  sh[tid] = s;
  __syncthreads();
  for (int d = 1; d < 1024; d <<= 1) {
    int v = (tid >= d) ? sh[tid - d] : 0;
    __syncthreads();
    sh[tid] += v;
    __syncthreads();
  }
  int excl = tid ? sh[tid - 1] : 0;
#pragma unroll
  for (int j = 0; j < ITEMS; ++j) { off[base + j] = excl; cur[base + j] = excl; excl += local[j]; }
  if (tid == 1023) off[n] = excl;
}

__global__ __launch_bounds__(1024) void k_scan(const int* __restrict__ rcnt, int* __restrict__ roff,
                                               int* __restrict__ rcur,
                                               const int* __restrict__ ccnt, int* __restrict__ coff,
                                               int* __restrict__ ccur) {
  __shared__ int sh[1024];
  if (blockIdx.x == 0) scan_impl<1>(rcnt, NN, roff, rcur, sh);
  else                 scan_impl<8>(ccnt, NFD, coff, ccur, sh);
}

__global__ void k_fill(const int* __restrict__ ridx, const int* __restrict__ cidx,
                       int* __restrict__ rcur, int* __restrict__ ccur,
                       int* __restrict__ rsorted, int* __restrict__ csorted) {
  int e = blockIdx.x * 256 + threadIdx.x;
  if (e < ER) { int t = ridx[ER + e]; int p = atomicAdd(&rcur[t], 1); rsorted[p] = e; }
  if (e < EC) { int t = cidx[EC + e]; int p = atomicAdd(&ccur[t], 1); csorted[p] = e; }
}

// ---------------- layout transforms ----------------
// x_global [B,N,H,T] -> x_bt [B,T,N,H] and xt [B,N,T,H] (+positional enc)
__global__ void k_xpose(const float* __restrict__ xg, float* __restrict__ x_bt,
                        float* __restrict__ xt) {
  __shared__ float lds[64][17];
  int bn = blockIdx.x;
  int b = bn >> 10, n = bn & 1023;
  int tid = threadIdx.x;
  const float* src = xg + (size_t)bn * (HH * TT);
  for (int i = tid; i < 1024; i += 256) lds[i >> 4][i & 15] = src[i];
  __syncthreads();
  for (int i = tid; i < 1024; i += 256) {
    int t = i >> 6, h = i & 63;
    float v = lds[h][t];
    float div = expf(-(float)(h & ~1) * (9.210340371976184f / 64.f));
    float arg = (float)t * div;
    float pe = (h & 1) ? cosf(arg) : sinf(arg);
    xt[(size_t)bn * 1024 + i] = v + pe;
    x_bt[(((size_t)b * TT + t) * NN + n) * HH + h] = v;
  }
}

// per_feature_x [B,N,F,H,T] -> nodes [B,T,N*F,H] (+femb)
__global__ void k_nodes(const float* __restrict__ pfx, const float* __restrict__ femb,
                        float* __restrict__ nodes) {
  __shared__ float lds[64][17];
  int bnf = blockIdx.x;                 // (b*N+n)*F+f
  int f = bnf & 7;
  int n = (bnf >> 3) & 1023;
  int b = bnf >> 13;
  int tid = threadIdx.x;
  const float* src = pfx + (size_t)bnf * (HH * TT);
  for (int i = tid; i < 1024; i += 256) lds[i >> 4][i & 15] = src[i];
  __syncthreads();
  for (int i = tid; i < 1024; i += 256) {
    int t = i >> 6, h = i & 63;
    nodes[(((size_t)b * TT + t) * NFD + n * FF + f) * HH + h] = lds[h][t] + femb[f * HH + h];
  }
}

// ---------------- fused GNN row (gather + folded lin/upd GEMM + lrelu) ----------------
__device__ __forceinline__ void gnn_row(const float* __restrict__ slice, int node,
                                        const float* __restrict__ mw, const int* __restrict__ srcarr,
                                        const int* __restrict__ off, const int* __restrict__ sorted,
                                        const float* __restrict__ Wf, const float* __restrict__ vv,
                                        const float* __restrict__ Wbot, const float* __restrict__ updb,
                                        float* __restrict__ outrow) {
  float pr[64];
#pragma unroll
  for (int k = 0; k < 64; ++k) pr[k] = 0.f;
  float s = 0.f;
  int e0 = off[node], e1 = off[node + 1];
  for (int j = e0; j < e1; ++j) {
    int e = sorted[j];
    float w = mw[e];
    int src = srcarr[e];
    const float4* r4 = (const float4*)(slice + src * 64);
    s += w;
#pragma unroll
    for (int q = 0; q < 16; ++q) {
      float4 v = r4[q];
      pr[4 * q + 0] += w * v.x;
      pr[4 * q + 1] += w * v.y;
      pr[4 * q + 2] += w * v.z;
      pr[4 * q + 3] += w * v.w;
    }
  }
  float acc[64];
#pragma unroll
  for (int c = 0; c < 64; ++c) acc[c] = s * vv[c] + updb[c];
#pragma unroll
  for (int k = 0; k < 64; ++k) row_fma(acc, pr[k], Wf + k * 64);
  stream_gemm64(acc, slice + node * 64, Wbot);
#pragma unroll
  for (int c = 0; c < 64; ++c) {
    float a = acc[c];
    outrow[c] = a >= 0.f ? a : 0.01f * a;
  }
}

__global__ __launch_bounds__(256) void k_river(const float* __restrict__ x_bt,
                                               const float* __restrict__ mw_r,
                                               const int* __restrict__ ridx,
                                               const int* __restrict__ roff,
                                               const int* __restrict__ rsorted,
                                               const float* __restrict__ Wfr,
                                               const float* __restrict__ v_r,
                                               const float* __restrict__ r_upd_W,
                                               const float* __restrict__ r_upd_b,
                                               float* __restrict__ river_upd) {
  int idx = blockIdx.x * 256 + threadIdx.x;   // bt*N + n
  int n = idx & (NN - 1);
  int bt = idx >> 10;
  gnn_row(x_bt + (size_t)bt * NN * HH, n, mw_r, ridx, roff, rsorted, Wfr, v_r,
          r_upd_W + 64 * 64, r_upd_b, river_upd + (size_t)idx * HH);
}

__global__ __launch_bounds__(256) void k_causal(const float* __restrict__ nodes,
                                                const float* __restrict__ mw_c,
                                                const int* __restrict__ cidx,
                                                const int* __restrict__ coff,
                                                const int* __restrict__ csorted,
                                                const float* __restrict__ Wfc,
                                                const float* __restrict__ v_c,
                                                const float* __restrict__ c_upd_W,
                                                const float* __restrict__ c_upd_b,
                                                float* __restrict__ cupd) {
  int idx = blockIdx.x * 256 + threadIdx.x;   // bt*NF + nf
  int nf = idx & (NFD - 1);
  int bt = idx >> 13;
  gnn_row(nodes + (size_t)bt * NFD * HH, nf, mw_c, cidx, coff, csorted, Wfc, v_c,
          c_upd_W + 64 * 64, c_upd_b, cupd + (size_t)idx * HH);
}

// ---------------- pooling over F ----------------
__global__ void k_pool(const float* __restrict__ cupd, float* __restrict__ pooled) {
  int idx = blockIdx.x * 256 + threadIdx.x;   // bt*N*H + n*H + h
  int h = idx & 63;
  int n = (idx >> 6) & 1023;
  int bt = idx >> 16;
  const float* base = cupd + ((size_t)bt * NFD + n * FF) * HH + h;
  float s = 0.f;
#pragma unroll
  for (int f = 0; f < FF; ++f) s += base[f * HH];
  pooled[idx] = s * 0.125f;
}

// ---------------- per-feature LN + transpose to pf_out [B,N,F,H,T] ----------------
__global__ void k_pfout(const float* __restrict__ cupd, const float* __restrict__ g,
                        const float* __restrict__ be, float* __restrict__ pf_out) {
  __shared__ float lds[16][65];
  __shared__ float mi[16], rs[16];
  int bnf = blockIdx.x;                 // (b*N+n)*F+f
  int f = bnf & 7;
  int n = (bnf >> 3) & 1023;
  int b = bnf >> 13;
  int tid = threadIdx.x;
  for (int i = tid; i < 1024; i += 256) {
    int t = i >> 6, h = i & 63;
    lds[t][h] = cupd[(((size_t)b * TT + t) * NFD + n * FF + f) * HH + h];
  }
  __syncthreads();
  int t = tid >> 4, l = tid & 15;
  float sm = 0.f;
#pragma unroll
  for (int q = 0; q < 4; ++q) sm += lds[t][l + 16 * q];
  sm += __shfl_xor(sm, 1); sm += __shfl_xor(sm, 2); sm += __shfl_xor(sm, 4); sm += __shfl_xor(sm, 8);
  float m = sm * (1.f / 64.f);
  float sv = 0.f;
#pragma unroll
  for (int q = 0; q < 4; ++q) { float d = lds[t][l + 16 * q] - m; sv += d * d; }
  sv += __shfl_xor(sv, 1); sv += __shfl_xor(sv, 2); sv += __shfl_xor(sv, 4); sv += __shfl_xor(sv, 8);
  float inv = 1.f / sqrtf(sv * (1.f / 64.f) + 1e-5f);
  if (l == 0) { mi[t] = m; rs[t] = inv; }
  __syncthreads();
  float* out = pf_out + (size_t)bnf * (HH * TT);
  for (int i = tid; i < 1024; i += 256) {
    int h = i >> 4, tt = i & 15;
    out[i] = (lds[tt][h] - mi[tt]) * rs[tt] * g[h] + be[h];
  }
}

// ---------------- spatial fusion (silu) ----------------
__global__ __launch_bounds__(256) void k_sf(const float* __restrict__ river_upd,
                                            const float* __restrict__ pooled,
                                            const float* __restrict__ sf_W,
                                            const float* __restrict__ sf_b,
                                            float* __restrict__ x_spatial) {
  int idx = blockIdx.x * 256 + threadIdx.x;   // bt*N + n
  float acc[64];
#pragma unroll
  for (int c = 0; c < 64; ++c) acc[c] = sf_b[c];
  stream_gemm64(acc, river_upd + (size_t)idx * HH, sf_W);
  stream_gemm64(acc, pooled + (size_t)idx * HH, sf_W + 64 * 64);
  float* out = x_spatial + (size_t)idx * HH;
#pragma unroll
  for (int c = 0; c < 64; ++c) {
    float a = acc[c];
    out[c] = a / (1.f + expf(-a));
  }
}

// ---------------- fused tconv+f1 -> LN -> silu -> f2 -> transpose out ----------------
__global__ __launch_bounds__(256) void k_fuse(const float* __restrict__ xt,
                                              const float* __restrict__ x_spatial,
                                              const float* __restrict__ Wg,
                                              const float* __restrict__ cvec,
                                              const float* __restrict__ f1_W,
                                              const float* __restrict__ fln_g,
                                              const float* __restrict__ fln_b,
                                              const float* __restrict__ f2_W,
                                              const float* __restrict__ f2_b,
                                              float* __restrict__ x_out) {
  int idx = blockIdx.x * 256 + threadIdx.x;   // bn*T + t
  int t = idx & 15;
  int bn = idx >> 4;
  int b = bn >> 10, n = bn & 1023;
  float acc[64];
#pragma unroll
  for (int c = 0; c < 64; ++c) acc[c] = cvec[c];
  const float* xbase = xt + (size_t)bn * (TT * HH);
#pragma unroll
  for (int kk = 0; kk < 3; ++kk) {
    int tt2 = t + kk - 1;
    if (tt2 >= 0 && tt2 < TT)
      stream_gemm64(acc, xbase + tt2 * HH, Wg + kk * 64 * 64);
  }
  stream_gemm64(acc, x_spatial + (((size_t)b * TT + t) * NN + n) * HH, f1_W + 64 * 64);
  float m = 0.f;
#pragma unroll
  for (int c = 0; c < 64; ++c) m += acc[c];
  m *= (1.f / 64.f);
  float var = 0.f;
#pragma unroll
  for (int c = 0; c < 64; ++c) { float d = acc[c] - m; var += d * d; }
  var *= (1.f / 64.f);
  float inv = 1.f / sqrtf(var + 1e-5f);
#pragma unroll
  for (int c = 0; c < 64; ++c) {
    float z = (acc[c] - m) * inv * fln_g[c] + fln_b[c];
    acc[c] = z / (1.f + expf(-z));
  }
  float acc2[64];
#pragma unroll
  for (int o = 0; o < 64; ++o) acc2[o] = f2_b[o];
#pragma unroll
  for (int k = 0; k < 64; ++k) row_fma(acc2, acc[k], f2_W + k * 64);
  float* out = x_out + (size_t)bn * (HH * TT) + t;
#pragma unroll
  for (int h = 0; h < 64; ++h) out[h * TT] = acc2[h];
}

// ---------------- launch ----------------
extern "C" void kernel_launch(void* const* d_in, const int* in_sizes, int n_in,
                              void* d_out, int out_size, void* d_ws, size_t ws_size,
                              hipStream_t stream) {
  (void)in_sizes; (void)n_in; (void)out_size; (void)ws_size;
  const float* x_global     = (const float*)d_in[0];
  const float* per_feature  = (const float*)d_in[1];
  const float* r_edge_attr  = (const float*)d_in[2];
  const float* c_edge_w     = (const float*)d_in[3];
  const float* W_tc         = (const float*)d_in[4];
  const float* b_tc         = (const float*)d_in[5];
  const float* r_lin_W      = (const float*)d_in[6];
  const float* r_lin_b      = (const float*)d_in[7];
  const float* r_upd_W      = (const float*)d_in[8];
  const float* r_upd_b      = (const float*)d_in[9];
  const float* r_edge_W     = (const float*)d_in[10];
  const float* r_edge_b     = (const float*)d_in[11];
  const float* r_gate       = (const float*)d_in[12];
  const float* c_lin_W      = (const float*)d_in[13];
  const float* c_lin_b      = (const float*)d_in[14];
  const float* c_upd_W      = (const float*)d_in[15];
  const float* c_upd_b      = (const float*)d_in[16];
  const float* c_gate       = (const float*)d_in[17];
  const float* sf_W         = (const float*)d_in[18];
  const float* sf_b         = (const float*)d_in[19];
  const float* femb         = (const float*)d_in[20];
  const float* pfn_g        = (const float*)d_in[21];
  const float* pfn_b        = (const float*)d_in[22];
  const float* f1_W         = (const float*)d_in[23];
  const float* f1_b         = (const float*)d_in[24];
  const float* fln_g        = (const float*)d_in[25];
  const float* fln_b        = (const float*)d_in[26];
  const float* f2_W         = (const float*)d_in[27];
  const float* f2_b         = (const float*)d_in[28];
  const int*   ridx         = (const int*)d_in[29];
  const int*   cidx         = (const int*)d_in[30];

  float* out_f = (float*)d_out;
  float* x_out  = out_f;                       // [B,N,H,T] : 2097152
  float* pf_out = out_f + 2097152;             // [B,N,F,H,T]

  const size_t BTNFH = (size_t)BTT * NFD * HH; // 16777216
  const size_t BTNH  = (size_t)BTT * NN * HH;  // 2097152

  float* ws = (float*)d_ws;
  size_t o = 0;
  float* nodes      = ws + o; o += BTNFH;
  float* cupd       = ws + o; o += BTNFH;
  float* x_bt       = ws + o; o += BTNH;
  float* xt         = ws + o; o += BTNH;       // [B,N,T,H]
  float* river_upd  = ws + o; o += BTNH;
  float* pooled     = ws + o; o += BTNH;
  float* x_spatial  = ws + o; o += BTNH;
  float* mw_r       = ws + o; o += ER;
  float* mw_c       = ws + o; o += EC;
  float* Wfr        = ws + o; o += 4096;
  float* v_r        = ws + o; o += 64;
  float* Wfc        = ws + o; o += 4096;
  float* v_c        = ws + o; o += 64;
  float* Wg         = ws + o; o += 192 * 64;
  float* cvec       = ws + o; o += 64;
  int* ib = (int*)(ws + o);
  size_t io = 0;
  int* rcnt    = ib + io; io += NN;
  int* roff    = ib + io; io += NN + 1;
  int* rcur    = ib + io; io += NN;
  int* rsorted = ib + io; io += ER;
  int* ccnt    = ib + io; io += NFD;
  int* coff    = ib + io; io += NFD + 1;
  int* ccur    = ib + io; io += NFD;
  int* csorted = ib + io; io += EC;

  k_prep_edges<<<128, 256, 0, stream>>>(r_edge_attr, c_edge_w, r_edge_W, r_edge_b,
                                        r_gate, c_gate, mw_r, mw_c, rcnt, ccnt);
  k_prep_w<<<3, 256, 0, stream>>>(r_lin_W, r_upd_W, r_lin_b, c_lin_W, c_upd_W, c_lin_b,
                                  W_tc, b_tc, f1_W, f1_b, Wfr, v_r, Wfc, v_c, Wg, cvec);
  k_count<<<128, 256, 0, stream>>>(ridx, cidx, rcnt, ccnt);
  k_scan<<<2, 1024, 0, stream>>>(rcnt, roff, rcur, ccnt, coff, ccur);
  k_fill<<<128, 256, 0, stream>>>(ridx, cidx, rcur, ccur, rsorted, csorted);
  k_xpose<<<BB * NN, 256, 0, stream>>>(x_global, x_bt, xt);
  k_nodes<<<BB * NN * FF, 256, 0, stream>>>(per_feature, femb, nodes);
  k_river<<<128, 256, 0, stream>>>(x_bt, mw_r, ridx, roff, rsorted, Wfr, v_r,
                                   r_upd_W, r_upd_b, river_upd);
  k_causal<<<1024, 256, 0, stream>>>(nodes, mw_c, cidx, coff, csorted, Wfc, v_c,
                                     c_upd_W, c_upd_b, cupd);
  k_pool<<<8192, 256, 0, stream>>>(cupd, pooled);
  k_pfout<<<BB * NN * FF, 256, 0, stream>>>(cupd, pfn_g, pfn_b, pf_out);
  k_sf<<<128, 256, 0, stream>>>(river_upd, pooled, sf_W, sf_b, x_spatial);
  k_fuse<<<128, 256, 0, stream>>>(xt, x_spatial, Wg, cvec, f1_W, fln_g, fln_b,
                                  f2_W, f2_b, x_out);
}

// Round 3
// 514.127 us; speedup vs baseline: 1.6945x; 1.6945x over previous
//
#include <hip/hip_runtime.h>
#include <cstddef>

#define BB 2
#define NN 1024
#define FF 8
#define HH 64
#define TT 16
#define ER 8192
#define EC 32768
#define EA 4
#define NFD 8192   // N*F
#define BTT 32     // B*T
#define LDA 68     // padded LDS stride (floats)

// ---------------- tiled GEMM core ----------------
// 256 threads, 64x64 tile, thread owns 4 rows x 4 cols.
// At: transposed A in LDS, At[k*LDA + row]. Wt: W in LDS, Wt[k*LDA + col].
__device__ __forceinline__ void tile_gemm(const float* At, const float* Wt,
                                          float4 acc[4], int r0, int c0) {
#pragma unroll 8
  for (int k = 0; k < 64; ++k) {
    float4 a = *(const float4*)(At + k * LDA + r0);
    float4 b = *(const float4*)(Wt + k * LDA + c0);
    acc[0].x = fmaf(a.x, b.x, acc[0].x); acc[0].y = fmaf(a.x, b.y, acc[0].y);
    acc[0].z = fmaf(a.x, b.z, acc[0].z); acc[0].w = fmaf(a.x, b.w, acc[0].w);
    acc[1].x = fmaf(a.y, b.x, acc[1].x); acc[1].y = fmaf(a.y, b.y, acc[1].y);
    acc[1].z = fmaf(a.y, b.z, acc[1].z); acc[1].w = fmaf(a.y, b.w, acc[1].w);
    acc[2].x = fmaf(a.z, b.x, acc[2].x); acc[2].y = fmaf(a.z, b.y, acc[2].y);
    acc[2].z = fmaf(a.z, b.z, acc[2].z); acc[2].w = fmaf(a.z, b.w, acc[2].w);
    acc[3].x = fmaf(a.w, b.x, acc[3].x); acc[3].y = fmaf(a.w, b.y, acc[3].y);
    acc[3].z = fmaf(a.w, b.z, acc[3].z); acc[3].w = fmaf(a.w, b.w, acc[3].w);
  }
}

// copy 64x64 W (row-major) into LDS with pad
__device__ __forceinline__ void stage_W(float* Wt, const float* __restrict__ W, int tid) {
#pragma unroll
  for (int q = 0; q < 4; ++q) {
    int i = tid + q * 256;                 // float4 index, 1024 total
    int k = i >> 4, c4 = (i & 15) << 2;
    *(float4*)(Wt + k * LDA + c4) = *(const float4*)(W + k * 64 + c4);
  }
}

// stage one 64-row x 64-k A tile transposed; src = row pointer (or null -> zeros)
__device__ __forceinline__ void stage_AT(float* At, const float* __restrict__ src, int tid) {
  int row = tid >> 2, kc = (tid & 3) << 4;
  if (src) {
#pragma unroll
    for (int q = 0; q < 4; ++q) {
      float4 v = *(const float4*)(src + kc + q * 4);
      int k = kc + q * 4;
      At[(k + 0) * LDA + row] = v.x;
      At[(k + 1) * LDA + row] = v.y;
      At[(k + 2) * LDA + row] = v.z;
      At[(k + 3) * LDA + row] = v.w;
    }
  } else {
#pragma unroll
    for (int q = 0; q < 16; ++q) At[(kc + q) * LDA + row] = 0.f;
  }
}

#define FMA4(P, V) \
  P.x = fmaf(w, V.x, P.x); P.y = fmaf(w, V.y, P.y); \
  P.z = fmaf(w, V.z, P.z); P.w = fmaf(w, V.w, P.w);

// gathered-aggregate A tile (transposed) + per-row weight sum
__device__ __forceinline__ void stage_gather(float* At, float* s_sh,
                                             const float* __restrict__ slice, int rowbase,
                                             const float* __restrict__ mw,
                                             const int* __restrict__ srcarr,
                                             const int* __restrict__ off,
                                             const int* __restrict__ sorted, int tid) {
  int row = tid >> 2, kc = (tid & 3) << 4;
  float4 p0 = make_float4(0.f, 0.f, 0.f, 0.f), p1 = p0, p2 = p0, p3 = p0;
  float s = 0.f;
  int node = rowbase + row;
  int e0 = off[node], e1 = off[node + 1];
  for (int j = e0; j < e1; ++j) {
    int e = sorted[j];
    float w = mw[e];
    const float4* sp = (const float4*)(slice + (size_t)srcarr[e] * 64 + kc);
    float4 v0 = sp[0], v1 = sp[1], v2 = sp[2], v3 = sp[3];
    FMA4(p0, v0); FMA4(p1, v1); FMA4(p2, v2); FMA4(p3, v3);
    s += w;
  }
  At[(kc + 0) * LDA + row] = p0.x;  At[(kc + 1) * LDA + row] = p0.y;
  At[(kc + 2) * LDA + row] = p0.z;  At[(kc + 3) * LDA + row] = p0.w;
  At[(kc + 4) * LDA + row] = p1.x;  At[(kc + 5) * LDA + row] = p1.y;
  At[(kc + 6) * LDA + row] = p1.z;  At[(kc + 7) * LDA + row] = p1.w;
  At[(kc + 8) * LDA + row] = p2.x;  At[(kc + 9) * LDA + row] = p2.y;
  At[(kc + 10) * LDA + row] = p2.z; At[(kc + 11) * LDA + row] = p2.w;
  At[(kc + 12) * LDA + row] = p3.x; At[(kc + 13) * LDA + row] = p3.y;
  At[(kc + 14) * LDA + row] = p3.z; At[(kc + 15) * LDA + row] = p3.w;
  if ((tid & 3) == 0) s_sh[row] = s;
}

// ---------------- fused GNN kernel (river & causal) ----------------
__global__ __launch_bounds__(256, 4) void k_gnn(const float* __restrict__ base,
    const int* __restrict__ off, const int* __restrict__ sorted,
    const int* __restrict__ srcarr, const float* __restrict__ mw,
    const float* __restrict__ Wf, const float* __restrict__ Wbot,
    const float* __restrict__ vv, const float* __restrict__ bb,
    float* __restrict__ out, int ngShift, int rowsSlice) {
  __shared__ float At[64 * LDA];
  __shared__ float Wt[64 * LDA];
  __shared__ float s_sh[64];
  int tid = threadIdx.x;
  int bt = blockIdx.x >> ngShift;
  int ng = blockIdx.x & ((1 << ngShift) - 1);
  const float* slice = base + (size_t)bt * rowsSlice * 64;
  int rowbase = ng * 64;
  float4 z4 = make_float4(0.f, 0.f, 0.f, 0.f);
  float4 acc[4] = {z4, z4, z4, z4};
  int r0 = (tid >> 4) << 2, c0 = (tid & 15) << 2;

  stage_W(Wt, Wf, tid);
  stage_gather(At, s_sh, slice, rowbase, mw, srcarr, off, sorted, tid);
  __syncthreads();
  tile_gemm(At, Wt, acc, r0, c0);
  __syncthreads();

  stage_W(Wt, Wbot, tid);
  stage_AT(At, slice + (size_t)(rowbase + (tid >> 2)) * 64, tid);
  __syncthreads();
  tile_gemm(At, Wt, acc, r0, c0);

  float4 v4 = *(const float4*)(vv + c0);
  float4 b4 = *(const float4*)(bb + c0);
#pragma unroll
  for (int i = 0; i < 4; ++i) {
    int row = r0 + i;
    float sv = s_sh[row];
    float4 z;
    z.x = acc[i].x + sv * v4.x + b4.x;
    z.y = acc[i].y + sv * v4.y + b4.y;
    z.z = acc[i].z + sv * v4.z + b4.z;
    z.w = acc[i].w + sv * v4.w + b4.w;
    z.x = z.x >= 0.f ? z.x : 0.01f * z.x;
    z.y = z.y >= 0.f ? z.y : 0.01f * z.y;
    z.z = z.z >= 0.f ? z.z : 0.01f * z.z;
    z.w = z.w >= 0.f ? z.w : 0.01f * z.w;
    *(float4*)(out + ((size_t)bt * rowsSlice + rowbase + row) * 64 + c0) = z;
  }
}

// ---------------- spatial fusion ----------------
__global__ __launch_bounds__(256, 4) void k_sf2(const float* __restrict__ river_upd,
    const float* __restrict__ pooled, const float* __restrict__ sf_W,
    const float* __restrict__ sf_b, float* __restrict__ x_spatial) {
  __shared__ float At[64 * LDA];
  __shared__ float Wt[64 * LDA];
  int tid = threadIdx.x;
  int rowbase = blockIdx.x * 64;
  float4 z4 = make_float4(0.f, 0.f, 0.f, 0.f);
  float4 acc[4] = {z4, z4, z4, z4};
  int r0 = (tid >> 4) << 2, c0 = (tid & 15) << 2;

  stage_W(Wt, sf_W, tid);
  stage_AT(At, river_upd + (size_t)(rowbase + (tid >> 2)) * 64, tid);
  __syncthreads();
  tile_gemm(At, Wt, acc, r0, c0);
  __syncthreads();

  stage_W(Wt, sf_W + 4096, tid);
  stage_AT(At, pooled + (size_t)(rowbase + (tid >> 2)) * 64, tid);
  __syncthreads();
  tile_gemm(At, Wt, acc, r0, c0);

  float4 b4 = *(const float4*)(sf_b + c0);
#pragma unroll
  for (int i = 0; i < 4; ++i) {
    float4 z;
    z.x = acc[i].x + b4.x; z.y = acc[i].y + b4.y;
    z.z = acc[i].z + b4.z; z.w = acc[i].w + b4.w;
    z.x = z.x / (1.f + expf(-z.x)); z.y = z.y / (1.f + expf(-z.y));
    z.z = z.z / (1.f + expf(-z.z)); z.w = z.w / (1.f + expf(-z.w));
    *(float4*)(x_spatial + (size_t)(rowbase + r0 + i) * 64 + c0) = z;
  }
}

// ---------------- fused tconv+f1 -> LN -> silu -> f2 -> out ----------------
__global__ __launch_bounds__(256, 4) void k_fuse2(const float* __restrict__ xt,
    const float* __restrict__ xsp, const float* __restrict__ Wg,
    const float* __restrict__ cvec, const float* __restrict__ f1W,
    const float* __restrict__ flng, const float* __restrict__ flnb,
    const float* __restrict__ f2W, const float* __restrict__ f2b,
    float* __restrict__ x_out) {
  __shared__ float At[64 * LDA];
  __shared__ float Wt[64 * LDA];
  int tid = threadIdx.x;
  int bn0 = blockIdx.x * 4;
  int srow = tid >> 2;            // staging row: (bnl, t)
  int bnl = srow >> 4, t = srow & 15;
  int bn = bn0 + bnl;
  float4 z4 = make_float4(0.f, 0.f, 0.f, 0.f);
  float4 acc[4] = {z4, z4, z4, z4};
  int r0 = (tid >> 4) << 2, c0 = (tid & 15) << 2;

#pragma unroll
  for (int kt = 0; kt < 3; ++kt) {
    int t2 = t + kt - 1;
    const float* src = (t2 >= 0 && t2 < TT) ? xt + ((size_t)bn * TT + t2) * 64 : nullptr;
    stage_W(Wt, Wg + kt * 4096, tid);
    stage_AT(At, src, tid);
    __syncthreads();
    tile_gemm(At, Wt, acc, r0, c0);
    __syncthreads();
  }
  {
    int b = bn >> 10, n = bn & 1023;
    const float* src = xsp + ((size_t)(b * TT + t) * NN + n) * 64;
    stage_W(Wt, f1W + 4096, tid);
    stage_AT(At, src, tid);
    __syncthreads();
    tile_gemm(At, Wt, acc, r0, c0);
    __syncthreads();
  }

  // LN + silu on z = acc + cvec  (rows r0..r0+3 split across 16 cg lanes)
  float4 cv = *(const float4*)(cvec + c0);
  float4 g4 = *(const float4*)(flng + c0);
  float4 lb4 = *(const float4*)(flnb + c0);
  float4 zz[4];
#pragma unroll
  for (int i = 0; i < 4; ++i) {
    zz[i].x = acc[i].x + cv.x; zz[i].y = acc[i].y + cv.y;
    zz[i].z = acc[i].z + cv.z; zz[i].w = acc[i].w + cv.w;
    float ps = zz[i].x + zz[i].y + zz[i].z + zz[i].w;
    float pq = zz[i].x * zz[i].x + zz[i].y * zz[i].y + zz[i].z * zz[i].z + zz[i].w * zz[i].w;
    ps += __shfl_xor(ps, 1); pq += __shfl_xor(pq, 1);
    ps += __shfl_xor(ps, 2); pq += __shfl_xor(pq, 2);
    ps += __shfl_xor(ps, 4); pq += __shfl_xor(pq, 4);
    ps += __shfl_xor(ps, 8); pq += __shfl_xor(pq, 8);
    float m = ps * (1.f / 64.f);
    float var = pq * (1.f / 64.f) - m * m;
    float inv = rsqrtf(var + 1e-5f);
    float4 w;
    w.x = (zz[i].x - m) * inv * g4.x + lb4.x;
    w.y = (zz[i].y - m) * inv * g4.y + lb4.y;
    w.z = (zz[i].z - m) * inv * g4.z + lb4.z;
    w.w = (zz[i].w - m) * inv * g4.w + lb4.w;
    zz[i].x = w.x / (1.f + expf(-w.x));
    zz[i].y = w.y / (1.f + expf(-w.y));
    zz[i].z = w.z / (1.f + expf(-w.z));
    zz[i].w = w.w / (1.f + expf(-w.w));
  }
  // stage z transposed into At, f2W into Wt
#pragma unroll
  for (int i = 0; i < 4; ++i) {
    At[(c0 + 0) * LDA + r0 + i] = zz[i].x;
    At[(c0 + 1) * LDA + r0 + i] = zz[i].y;
    At[(c0 + 2) * LDA + r0 + i] = zz[i].z;
    At[(c0 + 3) * LDA + r0 + i] = zz[i].w;
  }
  stage_W(Wt, f2W, tid);
  __syncthreads();
  float4 acc2[4] = {z4, z4, z4, z4};
  tile_gemm(At, Wt, acc2, r0, c0);
  __syncthreads();
  // Zt = Wt reuse: store acc2 + f2b as [row][c]
  float4 f2b4 = *(const float4*)(f2b + c0);
#pragma unroll
  for (int i = 0; i < 4; ++i) {
    float4 o;
    o.x = acc2[i].x + f2b4.x; o.y = acc2[i].y + f2b4.y;
    o.z = acc2[i].z + f2b4.z; o.w = acc2[i].w + f2b4.w;
    *(float4*)(Wt + (r0 + i) * LDA + c0) = o;
  }
  __syncthreads();
  // coalesced transpose-out: x_out[bn][h][t]
#pragma unroll
  for (int q = 0; q < 4; ++q) {
    int idx = tid + q * 256;
    int fo = idx * 4;
    int bnl2 = fo >> 10, rem = fo & 1023;
    int c = rem >> 4, tt = rem & 15;
    float4 o;
    o.x = Wt[(bnl2 * 16 + tt + 0) * LDA + c];
    o.y = Wt[(bnl2 * 16 + tt + 1) * LDA + c];
    o.z = Wt[(bnl2 * 16 + tt + 2) * LDA + c];
    o.w = Wt[(bnl2 * 16 + tt + 3) * LDA + c];
    *(float4*)(x_out + (size_t)(bn0 + bnl2) * 1024 + rem) = o;
  }
}

// ---------------- edge prep ----------------
__global__ void k_prep_edges(const float* __restrict__ attr, const float* __restrict__ cw,
                             const float* __restrict__ reW, const float* __restrict__ reB,
                             const float* __restrict__ rgate, const float* __restrict__ cgate,
                             float* __restrict__ mw_r, float* __restrict__ mw_c,
                             int* __restrict__ rcnt, int* __restrict__ ccnt) {
  int i = blockIdx.x * 256 + threadIdx.x;
  if (i < EC) {
    float g = 1.f / (1.f + expf(-cgate[0]));
    mw_c[i] = fminf(fmaxf(g * cw[i], 0.f), 1.f);
  }
  if (i < ER) {
    float ew = reB[0];
#pragma unroll
    for (int a = 0; a < EA; ++a) ew += attr[i * EA + a] * reW[a];
    float g = 1.f / (1.f + expf(-rgate[0]));
    mw_r[i] = fminf(fmaxf(g * ew, 0.f), 1.f);
  }
  if (i < NN) rcnt[i] = 0;
  if (i < NFD) ccnt[i] = 0;
}

// ---------------- fused-weight precompute ----------------
__global__ void k_prep_w(const float* __restrict__ r_lin_W, const float* __restrict__ r_upd_W,
                         const float* __restrict__ r_lin_b,
                         const float* __restrict__ c_lin_W, const float* __restrict__ c_upd_W,
                         const float* __restrict__ c_lin_b,
                         const float* __restrict__ W_tc, const float* __restrict__ b_tc,
                         const float* __restrict__ f1_W, const float* __restrict__ f1_b,
                         float* __restrict__ Wfr, float* __restrict__ v_r,
                         float* __restrict__ Wfc, float* __restrict__ v_c,
                         float* __restrict__ Wg, float* __restrict__ cvec) {
  int tid = threadIdx.x;
  if (blockIdx.x == 0) {
    for (int idx = tid; idx < 4096; idx += 256) {
      int k = idx >> 6, j = idx & 63;
      float s = 0.f;
      for (int m = 0; m < 64; ++m) s += r_lin_W[k * 64 + m] * r_upd_W[m * 64 + j];
      Wfr[idx] = s;
    }
    if (tid < 64) {
      float s = 0.f;
      for (int m = 0; m < 64; ++m) s += r_lin_b[m] * r_upd_W[m * 64 + tid];
      v_r[tid] = s;
    }
  } else if (blockIdx.x == 1) {
    for (int idx = tid; idx < 4096; idx += 256) {
      int k = idx >> 6, j = idx & 63;
      float s = 0.f;
      for (int m = 0; m < 64; ++m) s += c_lin_W[k * 64 + m] * c_upd_W[m * 64 + j];
      Wfc[idx] = s;
    }
    if (tid < 64) {
      float s = 0.f;
      for (int m = 0; m < 64; ++m) s += c_lin_b[m] * c_upd_W[m * 64 + tid];
      v_c[tid] = s;
    }
  } else {
    for (int idx = tid; idx < 12288; idx += 256) {
      int r = idx >> 6, c = idx & 63;
      int kk = r >> 6, i = r & 63;
      float s = 0.f;
      for (int o = 0; o < 64; ++o) s += W_tc[o * 192 + i * 3 + kk] * f1_W[o * 64 + c];
      Wg[idx] = s;
    }
    if (tid < 64) {
      float s = f1_b[tid];
      for (int o = 0; o < 64; ++o) s += b_tc[o] * f1_W[o * 64 + tid];
      cvec[tid] = s;
    }
  }
}

// ---------------- CSR build ----------------
__global__ void k_count(const int* __restrict__ ridx, const int* __restrict__ cidx,
                        int* __restrict__ rcnt, int* __restrict__ ccnt) {
  int e = blockIdx.x * 256 + threadIdx.x;
  if (e < ER) atomicAdd(&rcnt[ridx[ER + e]], 1);
  if (e < EC) atomicAdd(&ccnt[cidx[EC + e]], 1);
}

template <int ITEMS>
__device__ __forceinline__ void scan_impl(const int* __restrict__ cnt, int n,
                                          int* __restrict__ off, int* __restrict__ cur,
                                          int* sh) {
  int tid = threadIdx.x;
  int local[ITEMS];
  int s = 0;
  int base = tid * ITEMS;
#pragma unroll
  for (int j = 0; j < ITEMS; ++j) { local[j] = cnt[base + j]; s += local[j]; }
  sh[tid] = s;
  __syncthreads();
  for (int d = 1; d < 1024; d <<= 1) {
    int v = (tid >= d) ? sh[tid - d] : 0;
    __syncthreads();
    sh[tid] += v;
    __syncthreads();
  }
  int excl = tid ? sh[tid - 1] : 0;
#pragma unroll
  for (int j = 0; j < ITEMS; ++j) { off[base + j] = excl; cur[base + j] = excl; excl += local[j]; }
  if (tid == 1023) off[n] = excl;
}

__global__ __launch_bounds__(1024) void k_scan(const int* __restrict__ rcnt, int* __restrict__ roff,
                                               int* __restrict__ rcur,
                                               const int* __restrict__ ccnt, int* __restrict__ coff,
                                               int* __restrict__ ccur) {
  __shared__ int sh[1024];
  if (blockIdx.x == 0) scan_impl<1>(rcnt, NN, roff, rcur, sh);
  else                 scan_impl<8>(ccnt, NFD, coff, ccur, sh);
}

__global__ void k_fill(const int* __restrict__ ridx, const int* __restrict__ cidx,
                       int* __restrict__ rcur, int* __restrict__ ccur,
                       int* __restrict__ rsorted, int* __restrict__ csorted) {
  int e = blockIdx.x * 256 + threadIdx.x;
  if (e < ER) { int t = ridx[ER + e]; int p = atomicAdd(&rcur[t], 1); rsorted[p] = e; }
  if (e < EC) { int t = cidx[EC + e]; int p = atomicAdd(&ccur[t], 1); csorted[p] = e; }
}

// ---------------- layout transforms ----------------
__global__ void k_xpose(const float* __restrict__ xg, float* __restrict__ x_bt,
                        float* __restrict__ xt) {
  __shared__ float lds[64][17];
  int bn = blockIdx.x;
  int b = bn >> 10, n = bn & 1023;
  int tid = threadIdx.x;
  const float* src = xg + (size_t)bn * (HH * TT);
  for (int i = tid; i < 1024; i += 256) lds[i >> 4][i & 15] = src[i];
  __syncthreads();
  for (int i = tid; i < 1024; i += 256) {
    int t = i >> 6, h = i & 63;
    float v = lds[h][t];
    float div = expf(-(float)(h & ~1) * (9.210340371976184f / 64.f));
    float arg = (float)t * div;
    float pe = (h & 1) ? cosf(arg) : sinf(arg);
    xt[(size_t)bn * 1024 + i] = v + pe;
    x_bt[(((size_t)b * TT + t) * NN + n) * HH + h] = v;
  }
}

__global__ void k_nodes(const float* __restrict__ pfx, const float* __restrict__ femb,
                        float* __restrict__ nodes) {
  __shared__ float lds[64][17];
  int bnf = blockIdx.x;
  int f = bnf & 7;
  int n = (bnf >> 3) & 1023;
  int b = bnf >> 13;
  int tid = threadIdx.x;
  const float* src = pfx + (size_t)bnf * (HH * TT);
  for (int i = tid; i < 1024; i += 256) lds[i >> 4][i & 15] = src[i];
  __syncthreads();
  for (int i = tid; i < 1024; i += 256) {
    int t = i >> 6, h = i & 63;
    nodes[(((size_t)b * TT + t) * NFD + n * FF + f) * HH + h] = lds[h][t] + femb[f * HH + h];
  }
}

// ---------------- pooling over F ----------------
__global__ void k_pool(const float* __restrict__ cupd, float* __restrict__ pooled) {
  int idx = blockIdx.x * 256 + threadIdx.x;
  int h = idx & 63;
  int n = (idx >> 6) & 1023;
  int bt = idx >> 16;
  const float* base = cupd + ((size_t)bt * NFD + n * FF) * HH + h;
  float s = 0.f;
#pragma unroll
  for (int f = 0; f < FF; ++f) s += base[f * HH];
  pooled[idx] = s * 0.125f;
}

// ---------------- per-feature LN + transpose to pf_out ----------------
__global__ void k_pfout(const float* __restrict__ cupd, const float* __restrict__ g,
                        const float* __restrict__ be, float* __restrict__ pf_out) {
  __shared__ float lds[16][65];
  __shared__ float mi[16], rs[16];
  int bnf = blockIdx.x;
  int f = bnf & 7;
  int n = (bnf >> 3) & 1023;
  int b = bnf >> 13;
  int tid = threadIdx.x;
  for (int i = tid; i < 1024; i += 256) {
    int t = i >> 6, h = i & 63;
    lds[t][h] = cupd[(((size_t)b * TT + t) * NFD + n * FF + f) * HH + h];
  }
  __syncthreads();
  int t = tid >> 4, l = tid & 15;
  float sm = 0.f;
#pragma unroll
  for (int q = 0; q < 4; ++q) sm += lds[t][l + 16 * q];
  sm += __shfl_xor(sm, 1); sm += __shfl_xor(sm, 2); sm += __shfl_xor(sm, 4); sm += __shfl_xor(sm, 8);
  float m = sm * (1.f / 64.f);
  float sv = 0.f;
#pragma unroll
  for (int q = 0; q < 4; ++q) { float d = lds[t][l + 16 * q] - m; sv += d * d; }
  sv += __shfl_xor(sv, 1); sv += __shfl_xor(sv, 2); sv += __shfl_xor(sv, 4); sv += __shfl_xor(sv, 8);
  float inv = 1.f / sqrtf(sv * (1.f / 64.f) + 1e-5f);
  if (l == 0) { mi[t] = m; rs[t] = inv; }
  __syncthreads();
  float* out = pf_out + (size_t)bnf * (HH * TT);
  for (int i = tid; i < 1024; i += 256) {
    int h = i >> 4, tt = i & 15;
    out[i] = (lds[tt][h] - mi[tt]) * rs[tt] * g[h] + be[h];
  }
}

// ---------------- launch ----------------
extern "C" void kernel_launch(void* const* d_in, const int* in_sizes, int n_in,
                              void* d_out, int out_size, void* d_ws, size_t ws_size,
                              hipStream_t stream) {
  (void)in_sizes; (void)n_in; (void)out_size; (void)ws_size;
  const float* x_global     = (const float*)d_in[0];
  const float* per_feature  = (const float*)d_in[1];
  const float* r_edge_attr  = (const float*)d_in[2];
  const float* c_edge_w     = (const float*)d_in[3];
  const float* W_tc         = (const float*)d_in[4];
  const float* b_tc         = (const float*)d_in[5];
  const float* r_lin_W      = (const float*)d_in[6];
  const float* r_lin_b      = (const float*)d_in[7];
  const float* r_upd_W      = (const float*)d_in[8];
  const float* r_upd_b      = (const float*)d_in[9];
  const float* r_edge_W     = (const float*)d_in[10];
  const float* r_edge_b     = (const float*)d_in[11];
  const float* r_gate       = (const float*)d_in[12];
  const float* c_lin_W      = (const float*)d_in[13];
  const float* c_lin_b      = (const float*)d_in[14];
  const float* c_upd_W      = (const float*)d_in[15];
  const float* c_upd_b      = (const float*)d_in[16];
  const float* c_gate       = (const float*)d_in[17];
  const float* sf_W         = (const float*)d_in[18];
  const float* sf_b         = (const float*)d_in[19];
  const float* femb         = (const float*)d_in[20];
  const float* pfn_g        = (const float*)d_in[21];
  const float* pfn_b        = (const float*)d_in[22];
  const float* f1_W         = (const float*)d_in[23];
  const float* f1_b         = (const float*)d_in[24];
  const float* fln_g        = (const float*)d_in[25];
  const float* fln_b        = (const float*)d_in[26];
  const float* f2_W         = (const float*)d_in[27];
  const float* f2_b         = (const float*)d_in[28];
  const int*   ridx         = (const int*)d_in[29];
  const int*   cidx         = (const int*)d_in[30];

  float* out_f = (float*)d_out;
  float* x_out  = out_f;
  float* pf_out = out_f + 2097152;

  const size_t BTNFH = (size_t)BTT * NFD * HH;
  const size_t BTNH  = (size_t)BTT * NN * HH;

  float* ws = (float*)d_ws;
  size_t o = 0;
  float* nodes      = ws + o; o += BTNFH;
  float* cupd       = ws + o; o += BTNFH;
  float* x_bt       = ws + o; o += BTNH;
  float* xt         = ws + o; o += BTNH;
  float* river_upd  = ws + o; o += BTNH;
  float* pooled     = ws + o; o += BTNH;
  float* x_spatial  = ws + o; o += BTNH;
  float* mw_r       = ws + o; o += ER;
  float* mw_c       = ws + o; o += EC;
  float* Wfr        = ws + o; o += 4096;
  float* v_r        = ws + o; o += 64;
  float* Wfc        = ws + o; o += 4096;
  float* v_c        = ws + o; o += 64;
  float* Wg         = ws + o; o += 192 * 64;
  float* cvec       = ws + o; o += 64;
  int* ib = (int*)(ws + o);
  size_t io = 0;
  int* rcnt    = ib + io; io += NN;
  int* roff    = ib + io; io += NN + 1;
  int* rcur    = ib + io; io += NN;
  int* rsorted = ib + io; io += ER;
  int* ccnt    = ib + io; io += NFD;
  int* coff    = ib + io; io += NFD + 1;
  int* ccur    = ib + io; io += NFD;
  int* csorted = ib + io; io += EC;

  k_prep_edges<<<128, 256, 0, stream>>>(r_edge_attr, c_edge_w, r_edge_W, r_edge_b,
                                        r_gate, c_gate, mw_r, mw_c, rcnt, ccnt);
  k_prep_w<<<3, 256, 0, stream>>>(r_lin_W, r_upd_W, r_lin_b, c_lin_W, c_upd_W, c_lin_b,
                                  W_tc, b_tc, f1_W, f1_b, Wfr, v_r, Wfc, v_c, Wg, cvec);
  k_count<<<128, 256, 0, stream>>>(ridx, cidx, rcnt, ccnt);
  k_scan<<<2, 1024, 0, stream>>>(rcnt, roff, rcur, ccnt, coff, ccur);
  k_fill<<<128, 256, 0, stream>>>(ridx, cidx, rcur, ccur, rsorted, csorted);
  k_xpose<<<BB * NN, 256, 0, stream>>>(x_global, x_bt, xt);
  k_nodes<<<BB * NN * FF, 256, 0, stream>>>(per_feature, femb, nodes);
  // river: 32 bt-slices x 16 row-groups
  k_gnn<<<BTT * 16, 256, 0, stream>>>(x_bt, roff, rsorted, ridx, mw_r,
                                      Wfr, r_upd_W + 4096, v_r, r_upd_b,
                                      river_upd, 4, NN);
  // causal: 32 bt-slices x 128 row-groups
  k_gnn<<<BTT * 128, 256, 0, stream>>>(nodes, coff, csorted, cidx, mw_c,
                                       Wfc, c_upd_W + 4096, v_c, c_upd_b,
                                       cupd, 7, NFD);
  k_pool<<<8192, 256, 0, stream>>>(cupd, pooled);
  k_pfout<<<BB * NN * FF, 256, 0, stream>>>(cupd, pfn_g, pfn_b, pf_out);
  k_sf2<<<512, 256, 0, stream>>>(river_upd, pooled, sf_W, sf_b, x_spatial);
  k_fuse2<<<512, 256, 0, stream>>>(xt, x_spatial, Wg, cvec, f1_W, fln_g, fln_b,
                                   f2_W, f2_b, x_out);
}

// Round 5
// 482.062 us; speedup vs baseline: 1.8072x; 1.0665x over previous
//
#include <hip/hip_runtime.h>
#include <cstddef>

#define BB 2
#define NN 1024
#define FF 8
#define HH 64
#define TT 16
#define ER 8192
#define EC 32768
#define EA 4
#define NFD 8192   // N*F
#define BTT 32     // B*T
#define LDA 68     // padded LDS stride (floats)

// ---------------- tiled GEMM core ----------------
// 256 threads, 64x64 tile, thread owns 4 rows x 4 cols.
// At is stored row-SWIZZLED: element (k,row) lives at At[k*LDA + (row ^ (((k>>4)&3)<<2))].
// Wt is plain padded: Wt[k*LDA + col].
__device__ __forceinline__ void tile_gemm(const float* At, const float* Wt,
                                          float4 acc[4], int r0, int c0) {
#pragma unroll 16
  for (int k = 0; k < 64; ++k) {
    int rsw = r0 ^ (((k >> 4) & 3) << 2);
    float4 a = *(const float4*)(At + k * LDA + rsw);
    float4 b = *(const float4*)(Wt + k * LDA + c0);
    acc[0].x = fmaf(a.x, b.x, acc[0].x); acc[0].y = fmaf(a.x, b.y, acc[0].y);
    acc[0].z = fmaf(a.x, b.z, acc[0].z); acc[0].w = fmaf(a.x, b.w, acc[0].w);
    acc[1].x = fmaf(a.y, b.x, acc[1].x); acc[1].y = fmaf(a.y, b.y, acc[1].y);
    acc[1].z = fmaf(a.y, b.z, acc[1].z); acc[1].w = fmaf(a.y, b.w, acc[1].w);
    acc[2].x = fmaf(a.z, b.x, acc[2].x); acc[2].y = fmaf(a.z, b.y, acc[2].y);
    acc[2].z = fmaf(a.z, b.z, acc[2].z); acc[2].w = fmaf(a.z, b.w, acc[2].w);
    acc[3].x = fmaf(a.w, b.x, acc[3].x); acc[3].y = fmaf(a.w, b.y, acc[3].y);
    acc[3].z = fmaf(a.w, b.z, acc[3].z); acc[3].w = fmaf(a.w, b.w, acc[3].w);
  }
}

// copy 64x64 W (row-major) into LDS with pad
__device__ __forceinline__ void stage_W(float* Wt, const float* __restrict__ W, int tid) {
#pragma unroll
  for (int q = 0; q < 4; ++q) {
    int i = tid + q * 256;                 // float4 index, 1024 total
    int k = i >> 4, c4 = (i & 15) << 2;
    *(float4*)(Wt + k * LDA + c4) = *(const float4*)(W + k * 64 + c4);
  }
}

// stage one 64-row x 64-k A tile transposed+swizzled; src = row pointer (or null -> zeros)
__device__ __forceinline__ void stage_AT(float* At, const float* __restrict__ src, int tid) {
  int row = tid >> 2, kc = (tid & 3) << 4;
  int rsw = row ^ ((tid & 3) << 2);        // (k>>4)&3 == tid&3 for k in [kc,kc+16)
  if (src) {
#pragma unroll
    for (int q = 0; q < 4; ++q) {
      float4 v = *(const float4*)(src + kc + q * 4);
      int k = kc + q * 4;
      At[(k + 0) * LDA + rsw] = v.x;
      At[(k + 1) * LDA + rsw] = v.y;
      At[(k + 2) * LDA + rsw] = v.z;
      At[(k + 3) * LDA + rsw] = v.w;
    }
  } else {
#pragma unroll
    for (int q = 0; q < 16; ++q) At[(kc + q) * LDA + rsw] = 0.f;
  }
}

#define FMA4(P, V) \
  P.x = fmaf(w, V.x, P.x); P.y = fmaf(w, V.y, P.y); \
  P.z = fmaf(w, V.z, P.z); P.w = fmaf(w, V.w, P.w);

// gathered-aggregate A tile (transposed+swizzled) + per-row weight sum
// eg: packed CSR entries {src, bits(w)}
__device__ __forceinline__ void stage_gather(float* At, float* s_sh,
                                             const float* __restrict__ slice, int rowbase,
                                             const int2* __restrict__ eg,
                                             const int* __restrict__ off, int tid) {
  int row = tid >> 2, kc = (tid & 3) << 4;
  int rsw = row ^ ((tid & 3) << 2);
  float4 p0 = make_float4(0.f, 0.f, 0.f, 0.f), p1 = p0, p2 = p0, p3 = p0;
  float s = 0.f;
  int node = rowbase + row;
  int e0 = off[node], e1 = off[node + 1];
  int j = e0;
  for (; j + 2 <= e1; j += 2) {
    int2 ea = eg[j], eb = eg[j + 1];
    float wa = __int_as_float(ea.y), wb = __int_as_float(eb.y);
    const float4* spa = (const float4*)(slice + (size_t)ea.x * 64 + kc);
    const float4* spb = (const float4*)(slice + (size_t)eb.x * 64 + kc);
    float4 a0 = spa[0], a1 = spa[1], a2 = spa[2], a3 = spa[3];
    float4 b0 = spb[0], b1 = spb[1], b2 = spb[2], b3 = spb[3];
    { float w = wa; FMA4(p0, a0); FMA4(p1, a1); FMA4(p2, a2); FMA4(p3, a3); }
    { float w = wb; FMA4(p0, b0); FMA4(p1, b1); FMA4(p2, b2); FMA4(p3, b3); }
    s += wa + wb;
  }
  if (j < e1) {
    int2 ea = eg[j];
    float w = __int_as_float(ea.y);
    const float4* spa = (const float4*)(slice + (size_t)ea.x * 64 + kc);
    float4 a0 = spa[0], a1 = spa[1], a2 = spa[2], a3 = spa[3];
    FMA4(p0, a0); FMA4(p1, a1); FMA4(p2, a2); FMA4(p3, a3);
    s += w;
  }
  At[(kc + 0) * LDA + rsw] = p0.x;  At[(kc + 1) * LDA + rsw] = p0.y;
  At[(kc + 2) * LDA + rsw] = p0.z;  At[(kc + 3) * LDA + rsw] = p0.w;
  At[(kc + 4) * LDA + rsw] = p1.x;  At[(kc + 5) * LDA + rsw] = p1.y;
  At[(kc + 6) * LDA + rsw] = p1.z;  At[(kc + 7) * LDA + rsw] = p1.w;
  At[(kc + 8) * LDA + rsw] = p2.x;  At[(kc + 9) * LDA + rsw] = p2.y;
  At[(kc + 10) * LDA + rsw] = p2.z; At[(kc + 11) * LDA + rsw] = p2.w;
  At[(kc + 12) * LDA + rsw] = p3.x; At[(kc + 13) * LDA + rsw] = p3.y;
  At[(kc + 14) * LDA + rsw] = p3.z; At[(kc + 15) * LDA + rsw] = p3.w;
  if ((tid & 3) == 0) s_sh[row] = s;
}

// ---------------- fused GNN kernel (river & causal; POOL fuses mean-over-F) ----------------
template <bool POOL>
__global__ __launch_bounds__(256, 4) void k_gnn(const float* __restrict__ base,
    const int* __restrict__ off, const int2* __restrict__ eg,
    const float* __restrict__ Wf, const float* __restrict__ Wbot,
    const float* __restrict__ vv, const float* __restrict__ bb,
    float* __restrict__ out, float* __restrict__ pooled,
    int ngShift, int rowsSlice) {
  __shared__ float At[64 * LDA];
  __shared__ float Wt[64 * LDA];
  __shared__ float s_sh[64];
  int tid = threadIdx.x;
  // XCD-locality swizzle: XCD = blockIdx%8 (round-robin heuristic); each XCD
  // owns 4 complete bt-slices so the 2MB slice stays L2-resident.
  int bid = blockIdx.x;
  int xcd = bid & 7;
  int slot = bid >> 3;
  int ng = slot & ((1 << ngShift) - 1);
  int bt = xcd + 8 * (slot >> ngShift);
  const float* slice = base + (size_t)bt * rowsSlice * 64;
  int rowbase = ng * 64;
  float4 z4 = make_float4(0.f, 0.f, 0.f, 0.f);
  float4 acc[4] = {z4, z4, z4, z4};
  int r0 = (tid >> 4) << 2, c0 = (tid & 15) << 2;

  stage_W(Wt, Wf, tid);
  stage_gather(At, s_sh, slice, rowbase, eg, off, tid);
  __syncthreads();
  tile_gemm(At, Wt, acc, r0, c0);
  __syncthreads();

  stage_W(Wt, Wbot, tid);
  stage_AT(At, slice + (size_t)(rowbase + (tid >> 2)) * 64, tid);
  __syncthreads();
  tile_gemm(At, Wt, acc, r0, c0);

  float4 v4 = *(const float4*)(vv + c0);
  float4 b4 = *(const float4*)(bb + c0);
  float4 zz[4];
#pragma unroll
  for (int i = 0; i < 4; ++i) {
    int row = r0 + i;
    float sv = s_sh[row];
    float4 z;
    z.x = acc[i].x + sv * v4.x + b4.x;
    z.y = acc[i].y + sv * v4.y + b4.y;
    z.z = acc[i].z + sv * v4.z + b4.z;
    z.w = acc[i].w + sv * v4.w + b4.w;
    z.x = z.x >= 0.f ? z.x : 0.01f * z.x;
    z.y = z.y >= 0.f ? z.y : 0.01f * z.y;
    z.z = z.z >= 0.f ? z.z : 0.01f * z.z;
    z.w = z.w >= 0.f ? z.w : 0.01f * z.w;
    zz[i] = z;
    *(float4*)(out + ((size_t)bt * rowsSlice + rowbase + row) * 64 + c0) = z;
  }

  if (POOL) {
    // rows of this block = 8 complete nodes x 8 features; thread owns 4 f's of
    // node r0>>3; partner (tid^16) owns the other 4 -> shfl combine, no LDS.
    float4 ps;
    ps.x = zz[0].x + zz[1].x + zz[2].x + zz[3].x;
    ps.y = zz[0].y + zz[1].y + zz[2].y + zz[3].y;
    ps.z = zz[0].z + zz[1].z + zz[2].z + zz[3].z;
    ps.w = zz[0].w + zz[1].w + zz[2].w + zz[3].w;
    ps.x += __shfl_xor(ps.x, 16);
    ps.y += __shfl_xor(ps.y, 16);
    ps.z += __shfl_xor(ps.z, 16);
    ps.w += __shfl_xor(ps.w, 16);
    if (((tid >> 4) & 1) == 0) {
      int nd = r0 >> 3;                       // 0..7
      float4 o;
      o.x = ps.x * 0.125f; o.y = ps.y * 0.125f;
      o.z = ps.z * 0.125f; o.w = ps.w * 0.125f;
      *(float4*)(pooled + ((size_t)bt * NN + (rowbase >> 3) + nd) * 64 + c0) = o;
    }
  }
}

// ---------------- spatial fusion ----------------
__global__ __launch_bounds__(256, 4) void k_sf2(const float* __restrict__ river_upd,
    const float* __restrict__ pooled, const float* __restrict__ sf_W,
    const float* __restrict__ sf_b, float* __restrict__ x_spatial) {
  __shared__ float At[64 * LDA];
  __shared__ float Wt[64 * LDA];
  int tid = threadIdx.x;
  int rowbase = blockIdx.x * 64;
  float4 z4 = make_float4(0.f, 0.f, 0.f, 0.f);
  float4 acc[4] = {z4, z4, z4, z4};
  int r0 = (tid >> 4) << 2, c0 = (tid & 15) << 2;

  stage_W(Wt, sf_W, tid);
  stage_AT(At, river_upd + (size_t)(rowbase + (tid >> 2)) * 64, tid);
  __syncthreads();
  tile_gemm(At, Wt, acc, r0, c0);
  __syncthreads();

  stage_W(Wt, sf_W + 4096, tid);
  stage_AT(At, pooled + (size_t)(rowbase + (tid >> 2)) * 64, tid);
  __syncthreads();
  tile_gemm(At, Wt, acc, r0, c0);

  float4 b4 = *(const float4*)(sf_b + c0);
#pragma unroll
  for (int i = 0; i < 4; ++i) {
    float4 z;
    z.x = acc[i].x + b4.x; z.y = acc[i].y + b4.y;
    z.z = acc[i].z + b4.z; z.w = acc[i].w + b4.w;
    z.x = z.x / (1.f + expf(-z.x)); z.y = z.y / (1.f + expf(-z.y));
    z.z = z.z / (1.f + expf(-z.z)); z.w = z.w / (1.f + expf(-z.w));
    *(float4*)(x_spatial + (size_t)(rowbase + r0 + i) * 64 + c0) = z;
  }
}

// ---------------- fused tconv+f1 -> LN -> silu -> f2 -> out ----------------
__global__ __launch_bounds__(256, 4) void k_fuse2(const float* __restrict__ xt,
    const float* __restrict__ xsp, const float* __restrict__ Wg,
    const float* __restrict__ cvec, const float* __restrict__ f1W,
    const float* __restrict__ flng, const float* __restrict__ flnb,
    const float* __restrict__ f2W, const float* __restrict__ f2b,
    float* __restrict__ x_out) {
  __shared__ float At[64 * LDA];
  __shared__ float Wt[64 * LDA];
  int tid = threadIdx.x;
  int bn0 = blockIdx.x * 4;
  int srow = tid >> 2;            // staging row: (bnl, t)
  int bnl = srow >> 4, t = srow & 15;
  int bn = bn0 + bnl;
  float4 z4 = make_float4(0.f, 0.f, 0.f, 0.f);
  float4 acc[4] = {z4, z4, z4, z4};
  int r0 = (tid >> 4) << 2, c0 = (tid & 15) << 2;

#pragma unroll
  for (int kt = 0; kt < 3; ++kt) {
    int t2 = t + kt - 1;
    const float* src = (t2 >= 0 && t2 < TT) ? xt + ((size_t)bn * TT + t2) * 64 : nullptr;
    stage_W(Wt, Wg + kt * 4096, tid);
    stage_AT(At, src, tid);
    __syncthreads();
    tile_gemm(At, Wt, acc, r0, c0);
    __syncthreads();
  }
  {
    int b = bn >> 10, n = bn & 1023;
    const float* src = xsp + ((size_t)(b * TT + t) * NN + n) * 64;
    stage_W(Wt, f1W + 4096, tid);
    stage_AT(At, src, tid);
    __syncthreads();
    tile_gemm(At, Wt, acc, r0, c0);
    __syncthreads();
  }

  // LN + silu on z = acc + cvec
  float4 cv = *(const float4*)(cvec + c0);
  float4 g4 = *(const float4*)(flng + c0);
  float4 lb4 = *(const float4*)(flnb + c0);
  float4 zz[4];
#pragma unroll
  for (int i = 0; i < 4; ++i) {
    zz[i].x = acc[i].x + cv.x; zz[i].y = acc[i].y + cv.y;
    zz[i].z = acc[i].z + cv.z; zz[i].w = acc[i].w + cv.w;
    float ps = zz[i].x + zz[i].y + zz[i].z + zz[i].w;
    float pq = zz[i].x * zz[i].x + zz[i].y * zz[i].y + zz[i].z * zz[i].z + zz[i].w * zz[i].w;
    ps += __shfl_xor(ps, 1); pq += __shfl_xor(pq, 1);
    ps += __shfl_xor(ps, 2); pq += __shfl_xor(pq, 2);
    ps += __shfl_xor(ps, 4); pq += __shfl_xor(pq, 4);
    ps += __shfl_xor(ps, 8); pq += __shfl_xor(pq, 8);
    float m = ps * (1.f / 64.f);
    float var = pq * (1.f / 64.f) - m * m;
    float inv = rsqrtf(var + 1e-5f);
    float4 w;
    w.x = (zz[i].x - m) * inv * g4.x + lb4.x;
    w.y = (zz[i].y - m) * inv * g4.y + lb4.y;
    w.z = (zz[i].z - m) * inv * g4.z + lb4.z;
    w.w = (zz[i].w - m) * inv * g4.w + lb4.w;
    zz[i].x = w.x / (1.f + expf(-w.x));
    zz[i].y = w.y / (1.f + expf(-w.y));
    zz[i].z = w.z / (1.f + expf(-w.z));
    zz[i].w = w.w / (1.f + expf(-w.w));
  }
  // stage z transposed into At (swizzle-consistent: k index = c0+j), f2W into Wt
  {
    int xsw = ((c0 >> 4) & 3) << 2;
#pragma unroll
    for (int i = 0; i < 4; ++i) {
      int rr = (r0 + i) ^ xsw;
      At[(c0 + 0) * LDA + rr] = zz[i].x;
      At[(c0 + 1) * LDA + rr] = zz[i].y;
      At[(c0 + 2) * LDA + rr] = zz[i].z;
      At[(c0 + 3) * LDA + rr] = zz[i].w;
    }
  }
  stage_W(Wt, f2W, tid);
  __syncthreads();
  float4 acc2[4] = {z4, z4, z4, z4};
  tile_gemm(At, Wt, acc2, r0, c0);
  __syncthreads();
  // store acc2 + f2b into Wt as [row][c]
  float4 f2b4 = *(const float4*)(f2b + c0);
#pragma unroll
  for (int i = 0; i < 4; ++i) {
    float4 o;
    o.x = acc2[i].x + f2b4.x; o.y = acc2[i].y + f2b4.y;
    o.z = acc2[i].z + f2b4.z; o.w = acc2[i].w + f2b4.w;
    *(float4*)(Wt + (r0 + i) * LDA + c0) = o;
  }
  __syncthreads();
  // coalesced transpose-out: x_out[bn][h][t]
#pragma unroll
  for (int q = 0; q < 4; ++q) {
    int idx = tid + q * 256;
    int fo = idx * 4;
    int bnl2 = fo >> 10, rem = fo & 1023;
    int c = rem >> 4, tt = rem & 15;
    float4 o;
    o.x = Wt[(bnl2 * 16 + tt + 0) * LDA + c];
    o.y = Wt[(bnl2 * 16 + tt + 1) * LDA + c];
    o.z = Wt[(bnl2 * 16 + tt + 2) * LDA + c];
    o.w = Wt[(bnl2 * 16 + tt + 3) * LDA + c];
    *(float4*)(x_out + (size_t)(bn0 + bnl2) * 1024 + rem) = o;
  }
}

// ---------------- edge prep ----------------
__global__ void k_prep_edges(const float* __restrict__ attr, const float* __restrict__ cw,
                             const float* __restrict__ reW, const float* __restrict__ reB,
                             const float* __restrict__ rgate, const float* __restrict__ cgate,
                             float* __restrict__ mw_r, float* __restrict__ mw_c,
                             int* __restrict__ rcnt, int* __restrict__ ccnt) {
  int i = blockIdx.x * 256 + threadIdx.x;
  if (i < EC) {
    float g = 1.f / (1.f + expf(-cgate[0]));
    mw_c[i] = fminf(fmaxf(g * cw[i], 0.f), 1.f);
  }
  if (i < ER) {
    float ew = reB[0];
#pragma unroll
    for (int a = 0; a < EA; ++a) ew += attr[i * EA + a] * reW[a];
    float g = 1.f / (1.f + expf(-rgate[0]));
    mw_r[i] = fminf(fmaxf(g * ew, 0.f), 1.f);
  }
  if (i < NN) rcnt[i] = 0;
  if (i < NFD) ccnt[i] = 0;
}

// ---------------- fused-weight precompute ----------------
__global__ void k_prep_w(const float* __restrict__ r_lin_W, const float* __restrict__ r_upd_W,
                         const float* __restrict__ r_lin_b,
                         const float* __restrict__ c_lin_W, const float* __restrict__ c_upd_W,
                         const float* __restrict__ c_lin_b,
                         const float* __restrict__ W_tc, const float* __restrict__ b_tc,
                         const float* __restrict__ f1_W, const float* __restrict__ f1_b,
                         float* __restrict__ Wfr, float* __restrict__ v_r,
                         float* __restrict__ Wfc, float* __restrict__ v_c,
                         float* __restrict__ Wg, float* __restrict__ cvec) {
  int tid = threadIdx.x;
  if (blockIdx.x == 0) {
    for (int idx = tid; idx < 4096; idx += 256) {
      int k = idx >> 6, j = idx & 63;
      float s = 0.f;
      for (int m = 0; m < 64; ++m) s += r_lin_W[k * 64 + m] * r_upd_W[m * 64 + j];
      Wfr[idx] = s;
    }
    if (tid < 64) {
      float s = 0.f;
      for (int m = 0; m < 64; ++m) s += r_lin_b[m] * r_upd_W[m * 64 + tid];
      v_r[tid] = s;
    }
  } else if (blockIdx.x == 1) {
    for (int idx = tid; idx < 4096; idx += 256) {
      int k = idx >> 6, j = idx & 63;
      float s = 0.f;
      for (int m = 0; m < 64; ++m) s += c_lin_W[k * 64 + m] * c_upd_W[m * 64 + j];
      Wfc[idx] = s;
    }
    if (tid < 64) {
      float s = 0.f;
      for (int m = 0; m < 64; ++m) s += c_lin_b[m] * c_upd_W[m * 64 + tid];
      v_c[tid] = s;
    }
  } else {
    for (int idx = tid; idx < 12288; idx += 256) {
      int r = idx >> 6, c = idx & 63;
      int kk = r >> 6, i = r & 63;
      float s = 0.f;
      for (int o = 0; o < 64; ++o) s += W_tc[o * 192 + i * 3 + kk] * f1_W[o * 64 + c];
      Wg[idx] = s;
    }
    if (tid < 64) {
      float s = f1_b[tid];
      for (int o = 0; o < 64; ++o) s += b_tc[o] * f1_W[o * 64 + tid];
      cvec[tid] = s;
    }
  }
}

// ---------------- CSR build ----------------
__global__ void k_count(const int* __restrict__ ridx, const int* __restrict__ cidx,
                        int* __restrict__ rcnt, int* __restrict__ ccnt) {
  int e = blockIdx.x * 256 + threadIdx.x;
  if (e < ER) atomicAdd(&rcnt[ridx[ER + e]], 1);
  if (e < EC) atomicAdd(&ccnt[cidx[EC + e]], 1);
}

template <int ITEMS>
__device__ __forceinline__ void scan_impl(const int* __restrict__ cnt, int n,
                                          int* __restrict__ off, int* __restrict__ cur,
                                          int* sh) {
  int tid = threadIdx.x;
  int local[ITEMS];
  int s = 0;
  int base = tid * ITEMS;
#pragma unroll
  for (int j = 0; j < ITEMS; ++j) { local[j] = cnt[base + j]; s += local[j]; }
  sh[tid] = s;
  __syncthreads();
  for (int d = 1; d < 1024; d <<= 1) {
    int v = (tid >= d) ? sh[tid - d] : 0;
    __syncthreads();
    sh[tid] += v;
    __syncthreads();
  }
  int excl = tid ? sh[tid - 1] : 0;
#pragma unroll
  for (int j = 0; j < ITEMS; ++j) { off[base + j] = excl; cur[base + j] = excl; excl += local[j]; }
  if (tid == 1023) off[n] = excl;
}

__global__ __launch_bounds__(1024) void k_scan(const int* __restrict__ rcnt, int* __restrict__ roff,
                                               int* __restrict__ rcur,
                                               const int* __restrict__ ccnt, int* __restrict__ coff,
                                               int* __restrict__ ccur) {
  __shared__ int sh[1024];
  if (blockIdx.x == 0) scan_impl<1>(rcnt, NN, roff, rcur, sh);
  else                 scan_impl<8>(ccnt, NFD, coff, ccur, sh);
}

// fill packed CSR: {src, bits(w)} per slot — one fewer indirection in gather
__global__ void k_fill(const int* __restrict__ ridx, const int* __restrict__ cidx,
                       const float* __restrict__ mw_r, const float* __restrict__ mw_c,
                       int* __restrict__ rcur, int* __restrict__ ccur,
                       int2* __restrict__ rpk, int2* __restrict__ cpk) {
  int e = blockIdx.x * 256 + threadIdx.x;
  if (e < ER) {
    int t = ridx[ER + e]; int p = atomicAdd(&rcur[t], 1);
    rpk[p] = make_int2(ridx[e], __float_as_int(mw_r[e]));
  }
  if (e < EC) {
    int t = cidx[EC + e]; int p = atomicAdd(&ccur[t], 1);
    cpk[p] = make_int2(cidx[e], __float_as_int(mw_c[e]));
  }
}

// ---------------- layout transforms ----------------
__global__ void k_xpose(const float* __restrict__ xg, float* __restrict__ x_bt,
                        float* __restrict__ xt) {
  __shared__ float lds[64][17];
  int bn = blockIdx.x;
  int b = bn >> 10, n = bn & 1023;
  int tid = threadIdx.x;
  const float* src = xg + (size_t)bn * (HH * TT);
  for (int i = tid; i < 1024; i += 256) lds[i >> 4][i & 15] = src[i];
  __syncthreads();
  for (int i = tid; i < 1024; i += 256) {
    int t = i >> 6, h = i & 63;
    float v = lds[h][t];
    float div = expf(-(float)(h & ~1) * (9.210340371976184f / 64.f));
    float arg = (float)t * div;
    float pe = (h & 1) ? cosf(arg) : sinf(arg);
    xt[(size_t)bn * 1024 + i] = v + pe;
    x_bt[(((size_t)b * TT + t) * NN + n) * HH + h] = v;
  }
}

__global__ void k_nodes(const float* __restrict__ pfx, const float* __restrict__ femb,
                        float* __restrict__ nodes) {
  __shared__ float lds[64][17];
  int bnf = blockIdx.x;
  int f = bnf & 7;
  int n = (bnf >> 3) & 1023;
  int b = bnf >> 13;
  int tid = threadIdx.x;
  const float* src = pfx + (size_t)bnf * (HH * TT);
  for (int i = tid; i < 1024; i += 256) lds[i >> 4][i & 15] = src[i];
  __syncthreads();
  for (int i = tid; i < 1024; i += 256) {
    int t = i >> 6, h = i & 63;
    nodes[(((size_t)b * TT + t) * NFD + n * FF + f) * HH + h] = lds[h][t] + femb[f * HH + h];
  }
}

// ---------------- per-feature LN + transpose to pf_out ----------------
__global__ void k_pfout(const float* __restrict__ cupd, const float* __restrict__ g,
                        const float* __restrict__ be, float* __restrict__ pf_out) {
  __shared__ float lds[16][65];
  __shared__ float mi[16], rs[16];
  int bnf = blockIdx.x;
  int f = bnf & 7;
  int n = (bnf >> 3) & 1023;
  int b = bnf >> 13;
  int tid = threadIdx.x;
  for (int i = tid; i < 1024; i += 256) {
    int t = i >> 6, h = i & 63;
    lds[t][h] = cupd[(((size_t)b * TT + t) * NFD + n * FF + f) * HH + h];
  }
  __syncthreads();
  int t = tid >> 4, l = tid & 15;
  float sm = 0.f;
#pragma unroll
  for (int q = 0; q < 4; ++q) sm += lds[t][l + 16 * q];
  sm += __shfl_xor(sm, 1); sm += __shfl_xor(sm, 2); sm += __shfl_xor(sm, 4); sm += __shfl_xor(sm, 8);
  float m = sm * (1.f / 64.f);
  float sv = 0.f;
#pragma unroll
  for (int q = 0; q < 4; ++q) { float d = lds[t][l + 16 * q] - m; sv += d * d; }
  sv += __shfl_xor(sv, 1); sv += __shfl_xor(sv, 2); sv += __shfl_xor(sv, 4); sv += __shfl_xor(sv, 8);
  float inv = 1.f / sqrtf(sv * (1.f / 64.f) + 1e-5f);
  if (l == 0) { mi[t] = m; rs[t] = inv; }
  __syncthreads();
  float* out = pf_out + (size_t)bnf * (HH * TT);
  for (int i = tid; i < 1024; i += 256) {
    int h = i >> 4, tt = i & 15;
    out[i] = (lds[tt][h] - mi[tt]) * rs[tt] * g[h] + be[h];
  }
}

// ---------------- launch ----------------
extern "C" void kernel_launch(void* const* d_in, const int* in_sizes, int n_in,
                              void* d_out, int out_size, void* d_ws, size_t ws_size,
                              hipStream_t stream) {
  (void)in_sizes; (void)n_in; (void)out_size; (void)ws_size;
  const float* x_global     = (const float*)d_in[0];
  const float* per_feature  = (const float*)d_in[1];
  const float* r_edge_attr  = (const float*)d_in[2];
  const float* c_edge_w     = (const float*)d_in[3];
  const float* W_tc         = (const float*)d_in[4];
  const float* b_tc         = (const float*)d_in[5];
  const float* r_lin_W      = (const float*)d_in[6];
  const float* r_lin_b      = (const float*)d_in[7];
  const float* r_upd_W      = (const float*)d_in[8];
  const float* r_upd_b      = (const float*)d_in[9];
  const float* r_edge_W     = (const float*)d_in[10];
  const float* r_edge_b     = (const float*)d_in[11];
  const float* r_gate       = (const float*)d_in[12];
  const float* c_lin_W      = (const float*)d_in[13];
  const float* c_lin_b      = (const float*)d_in[14];
  const float* c_upd_W      = (const float*)d_in[15];
  const float* c_upd_b      = (const float*)d_in[16];
  const float* c_gate       = (const float*)d_in[17];
  const float* sf_W         = (const float*)d_in[18];
  const float* sf_b         = (const float*)d_in[19];
  const float* femb         = (const float*)d_in[20];
  const float* pfn_g        = (const float*)d_in[21];
  const float* pfn_b        = (const float*)d_in[22];
  const float* f1_W         = (const float*)d_in[23];
  const float* f1_b         = (const float*)d_in[24];
  const float* fln_g        = (const float*)d_in[25];
  const float* fln_b        = (const float*)d_in[26];
  const float* f2_W         = (const float*)d_in[27];
  const float* f2_b         = (const float*)d_in[28];
  const int*   ridx         = (const int*)d_in[29];
  const int*   cidx         = (const int*)d_in[30];

  float* out_f = (float*)d_out;
  float* x_out  = out_f;
  float* pf_out = out_f + 2097152;

  const size_t BTNFH = (size_t)BTT * NFD * HH;
  const size_t BTNH  = (size_t)BTT * NN * HH;

  float* ws = (float*)d_ws;
  size_t o = 0;
  float* nodes      = ws + o; o += BTNFH;
  float* cupd       = ws + o; o += BTNFH;
  float* x_bt       = ws + o; o += BTNH;
  float* xt         = ws + o; o += BTNH;
  float* river_upd  = ws + o; o += BTNH;
  float* pooled     = ws + o; o += BTNH;
  float* x_spatial  = ws + o; o += BTNH;
  float* mw_r       = ws + o; o += ER;
  float* mw_c       = ws + o; o += EC;
  float* Wfr        = ws + o; o += 4096;
  float* v_r        = ws + o; o += 64;
  float* Wfc        = ws + o; o += 4096;
  float* v_c        = ws + o; o += 64;
  float* Wg         = ws + o; o += 192 * 64;
  float* cvec       = ws + o; o += 64;
  // int region (o is even -> 8B aligned); int2 arrays first
  int2* rpk = (int2*)(ws + o);                 // ER entries
  int2* cpk = rpk + ER;                        // EC entries
  int* ib = (int*)(cpk + EC);
  size_t io = 0;
  int* rcnt    = ib + io; io += NN;
  int* roff    = ib + io; io += NN + 1;
  int* rcur    = ib + io; io += NN + 1;
  int* ccnt    = ib + io; io += NFD;
  int* coff    = ib + io; io += NFD + 1;
  int* ccur    = ib + io; io += NFD + 1;

  k_prep_edges<<<128, 256, 0, stream>>>(r_edge_attr, c_edge_w, r_edge_W, r_edge_b,
                                        r_gate, c_gate, mw_r, mw_c, rcnt, ccnt);
  k_prep_w<<<3, 256, 0, stream>>>(r_lin_W, r_upd_W, r_lin_b, c_lin_W, c_upd_W, c_lin_b,
                                  W_tc, b_tc, f1_W, f1_b, Wfr, v_r, Wfc, v_c, Wg, cvec);
  k_count<<<128, 256, 0, stream>>>(ridx, cidx, rcnt, ccnt);
  k_scan<<<2, 1024, 0, stream>>>(rcnt, roff, rcur, ccnt, coff, ccur);
  k_fill<<<128, 256, 0, stream>>>(ridx, cidx, mw_r, mw_c, rcur, ccur, rpk, cpk);
  k_xpose<<<BB * NN, 256, 0, stream>>>(x_global, x_bt, xt);
  k_nodes<<<BB * NN * FF, 256, 0, stream>>>(per_feature, femb, nodes);
  // river: 512 blocks = 8 xcd x (4 bt x 16 ng)
  k_gnn<false><<<BTT * 16, 256, 0, stream>>>(x_bt, roff, rpk,
                                             Wfr, r_upd_W + 4096, v_r, r_upd_b,
                                             river_upd, nullptr, 4, NN);
  // causal: 4096 blocks = 8 xcd x (4 bt x 128 ng); fuses pool-over-F
  k_gnn<true><<<BTT * 128, 256, 0, stream>>>(nodes, coff, cpk,
                                             Wfc, c_upd_W + 4096, v_c, c_upd_b,
                                             cupd, pooled, 7, NFD);
  k_pfout<<<BB * NN * FF, 256, 0, stream>>>(cupd, pfn_g, pfn_b, pf_out);
  k_sf2<<<512, 256, 0, stream>>>(river_upd, pooled, sf_W, sf_b, x_spatial);
  k_fuse2<<<512, 256, 0, stream>>>(xt, x_spatial, Wg, cvec, f1_W, fln_g, fln_b,
                                   f2_W, f2_b, x_out);
}

// Round 7
// 421.607 us; speedup vs baseline: 2.0664x; 1.1434x over previous
//
#include <hip/hip_runtime.h>
#include <cstddef>

#define BB 2
#define NN 1024
#define FF 8
#define HH 64
#define TT 16
#define ER 8192
#define EC 32768
#define EA 4
#define NFD 8192   // N*F
#define BTT 32     // B*T
#define LDA 68     // padded LDS stride (floats)

// ---------------- tiled GEMM core ----------------
// 256 threads, 64x64 tile, thread owns 4 rows x 4 cols.
// At is stored row-SWIZZLED: element (k,row) lives at At[k*LDA + (row ^ (((k>>4)&3)<<2))].
__device__ __forceinline__ void tile_gemm(const float* At, const float* Wt,
                                          float4 acc[4], int r0, int c0) {
#pragma unroll 16
  for (int k = 0; k < 64; ++k) {
    int rsw = r0 ^ (((k >> 4) & 3) << 2);
    float4 a = *(const float4*)(At + k * LDA + rsw);
    float4 b = *(const float4*)(Wt + k * LDA + c0);
    acc[0].x = fmaf(a.x, b.x, acc[0].x); acc[0].y = fmaf(a.x, b.y, acc[0].y);
    acc[0].z = fmaf(a.x, b.z, acc[0].z); acc[0].w = fmaf(a.x, b.w, acc[0].w);
    acc[1].x = fmaf(a.y, b.x, acc[1].x); acc[1].y = fmaf(a.y, b.y, acc[1].y);
    acc[1].z = fmaf(a.y, b.z, acc[1].z); acc[1].w = fmaf(a.y, b.w, acc[1].w);
    acc[2].x = fmaf(a.z, b.x, acc[2].x); acc[2].y = fmaf(a.z, b.y, acc[2].y);
    acc[2].z = fmaf(a.z, b.z, acc[2].z); acc[2].w = fmaf(a.z, b.w, acc[2].w);
    acc[3].x = fmaf(a.w, b.x, acc[3].x); acc[3].y = fmaf(a.w, b.y, acc[3].y);
    acc[3].z = fmaf(a.w, b.z, acc[3].z); acc[3].w = fmaf(a.w, b.w, acc[3].w);
  }
}

__device__ __forceinline__ void stage_W(float* Wt, const float* __restrict__ W, int tid) {
#pragma unroll
  for (int q = 0; q < 4; ++q) {
    int i = tid + q * 256;
    int k = i >> 4, c4 = (i & 15) << 2;
    *(float4*)(Wt + k * LDA + c4) = *(const float4*)(W + k * 64 + c4);
  }
}

// dense 64-row A tile, transposed+swizzled (4 lanes/row)
__device__ __forceinline__ void stage_AT(float* At, const float* __restrict__ src, int tid) {
  int row = tid >> 2, kc = (tid & 3) << 4;
  int rsw = row ^ ((tid & 3) << 2);
  if (src) {
#pragma unroll
    for (int q = 0; q < 4; ++q) {
      float4 v = *(const float4*)(src + kc + q * 4);
      int k = kc + q * 4;
      At[(k + 0) * LDA + rsw] = v.x;
      At[(k + 1) * LDA + rsw] = v.y;
      At[(k + 2) * LDA + rsw] = v.z;
      At[(k + 3) * LDA + rsw] = v.w;
    }
  } else {
#pragma unroll
    for (int q = 0; q < 16; ++q) At[(kc + q) * LDA + rsw] = 0.f;
  }
}

#define GFMA(ACC, W, V) \
  ACC.x = fmaf(W, V.x, ACC.x); ACC.y = fmaf(W, V.y, ACC.y); \
  ACC.z = fmaf(W, V.z, ACC.z); ACC.w = fmaf(W, V.w, ACC.w);

// gathered-aggregate A tile: 16 lanes/row (divergence = max over 4 rows/wave),
// 4 passes of 16 rows, 4-edge unroll for MLP.
__device__ __forceinline__ void stage_gather16(float* At, float* s_sh,
                                               const float* __restrict__ slice, int rowbase,
                                               const int2* __restrict__ eg,
                                               const int* __restrict__ off, int tid) {
  int rloc = tid >> 4;            // 0..15
  int lane = tid & 15;            // 0..15
  int kc = lane << 2;             // float offset
  int xsw = (lane >> 2) << 2;     // ((kc>>4)&3)<<2, same for kc..kc+3
#pragma unroll
  for (int p = 0; p < 4; ++p) {
    int row = p * 16 + rloc;
    int node = rowbase + row;
    int e0 = off[node], e1 = off[node + 1];
    float4 acc = make_float4(0.f, 0.f, 0.f, 0.f);
    float s = 0.f;
    int j = e0;
    for (; j + 4 <= e1; j += 4) {
      int2 e_0 = eg[j], e_1 = eg[j + 1], e_2 = eg[j + 2], e_3 = eg[j + 3];
      float w0 = __int_as_float(e_0.y), w1 = __int_as_float(e_1.y);
      float w2 = __int_as_float(e_2.y), w3 = __int_as_float(e_3.y);
      float4 v0 = *(const float4*)(slice + (size_t)e_0.x * 64 + kc);
      float4 v1 = *(const float4*)(slice + (size_t)e_1.x * 64 + kc);
      float4 v2 = *(const float4*)(slice + (size_t)e_2.x * 64 + kc);
      float4 v3 = *(const float4*)(slice + (size_t)e_3.x * 64 + kc);
      GFMA(acc, w0, v0); GFMA(acc, w1, v1); GFMA(acc, w2, v2); GFMA(acc, w3, v3);
      s += w0 + w1 + w2 + w3;
    }
    for (; j < e1; ++j) {
      int2 e_0 = eg[j];
      float w0 = __int_as_float(e_0.y);
      float4 v0 = *(const float4*)(slice + (size_t)e_0.x * 64 + kc);
      GFMA(acc, w0, v0);
      s += w0;
    }
    int rsw = row ^ xsw;
    At[(kc + 0) * LDA + rsw] = acc.x;
    At[(kc + 1) * LDA + rsw] = acc.y;
    At[(kc + 2) * LDA + rsw] = acc.z;
    At[(kc + 3) * LDA + rsw] = acc.w;
    if (lane == 0) s_sh[row] = s;
  }
}

// ---------------- combined GNN kernel (river blocks 0..511, causal 512..4607) ----------------
__global__ __launch_bounds__(256, 4) void k_gnn(
    const float* __restrict__ xbt, const float* __restrict__ nodes,
    const int* __restrict__ roff, const int2* __restrict__ rpk,
    const int* __restrict__ coff, const int2* __restrict__ cpk,
    const float* __restrict__ Wfr, const float* __restrict__ rWbot,
    const float* __restrict__ v_r, const float* __restrict__ r_b,
    const float* __restrict__ Wfc, const float* __restrict__ cWbot,
    const float* __restrict__ v_c, const float* __restrict__ c_b,
    float* __restrict__ river_out, float* __restrict__ cupd,
    float* __restrict__ pooled) {
  __shared__ float At[64 * LDA];
  __shared__ float Wt[64 * LDA];
  __shared__ float s_sh[64];
  int tid = threadIdx.x;
  int bid = blockIdx.x;
  const float *base, *Wf, *Wbot, *vv, *bb;
  const int* off; const int2* eg;
  float* out; float* pool;
  int rowsSlice, rowbase, bt;
  if (bid < 512) {                       // river: 8 xcd x (16 ng x 4 btg)
    int xcd = bid & 7, slot = bid >> 3;
    rowsSlice = NN; rowbase = (slot & 15) * 64; bt = xcd + 8 * (slot >> 4);
    base = xbt; off = roff; eg = rpk;
    Wf = Wfr; Wbot = rWbot; vv = v_r; bb = r_b;
    out = river_out; pool = nullptr;
  } else {                               // causal: 8 xcd x (128 ng x 4 btg)
    int cb = bid - 512;
    int xcd = cb & 7, slot = cb >> 3;
    rowsSlice = NFD; rowbase = (slot & 127) * 64; bt = xcd + 8 * (slot >> 7);
    base = nodes; off = coff; eg = cpk;
    Wf = Wfc; Wbot = cWbot; vv = v_c; bb = c_b;
    out = cupd; pool = pooled;
  }
  const float* slice = base + (size_t)bt * rowsSlice * 64;
  float4 z4 = make_float4(0.f, 0.f, 0.f, 0.f);
  float4 acc[4] = {z4, z4, z4, z4};
  int r0 = (tid >> 4) << 2, c0 = (tid & 15) << 2;

  stage_W(Wt, Wf, tid);
  stage_gather16(At, s_sh, slice, rowbase, eg, off, tid);
  __syncthreads();
  tile_gemm(At, Wt, acc, r0, c0);
  __syncthreads();

  stage_W(Wt, Wbot, tid);
  stage_AT(At, slice + (size_t)(rowbase + (tid >> 2)) * 64, tid);
  __syncthreads();
  tile_gemm(At, Wt, acc, r0, c0);

  float4 v4 = *(const float4*)(vv + c0);
  float4 b4 = *(const float4*)(bb + c0);
  float4 zz[4];
#pragma unroll
  for (int i = 0; i < 4; ++i) {
    int row = r0 + i;
    float sv = s_sh[row];
    float4 z;
    z.x = acc[i].x + sv * v4.x + b4.x;
    z.y = acc[i].y + sv * v4.y + b4.y;
    z.z = acc[i].z + sv * v4.z + b4.z;
    z.w = acc[i].w + sv * v4.w + b4.w;
    z.x = z.x >= 0.f ? z.x : 0.01f * z.x;
    z.y = z.y >= 0.f ? z.y : 0.01f * z.y;
    z.z = z.z >= 0.f ? z.z : 0.01f * z.z;
    z.w = z.w >= 0.f ? z.w : 0.01f * z.w;
    zz[i] = z;
    *(float4*)(out + ((size_t)bt * rowsSlice + rowbase + row) * 64 + c0) = z;
  }

  if (pool) {
    float4 ps;
    ps.x = zz[0].x + zz[1].x + zz[2].x + zz[3].x;
    ps.y = zz[0].y + zz[1].y + zz[2].y + zz[3].y;
    ps.z = zz[0].z + zz[1].z + zz[2].z + zz[3].z;
    ps.w = zz[0].w + zz[1].w + zz[2].w + zz[3].w;
    ps.x += __shfl_xor(ps.x, 16);
    ps.y += __shfl_xor(ps.y, 16);
    ps.z += __shfl_xor(ps.z, 16);
    ps.w += __shfl_xor(ps.w, 16);
    if (((tid >> 4) & 1) == 0) {
      int nd = r0 >> 3;
      float4 o;
      o.x = ps.x * 0.125f; o.y = ps.y * 0.125f;
      o.z = ps.z * 0.125f; o.w = ps.w * 0.125f;
      *(float4*)(pooled + ((size_t)bt * NN + (rowbase >> 3) + nd) * 64 + c0) = o;
    }
  }
}

// ---------------- post: sf2 (blocks 0..511) + pfout (512..16895) ----------------
__global__ __launch_bounds__(256, 4) void k_post(
    const float* __restrict__ river_upd, const float* __restrict__ pooled,
    const float* __restrict__ sf_W, const float* __restrict__ sf_b,
    float* __restrict__ x_spatial,
    const float* __restrict__ cupd, const float* __restrict__ g,
    const float* __restrict__ be, float* __restrict__ pf_out) {
  __shared__ float At[64 * LDA];
  __shared__ float Wt[64 * LDA];
  int tid = threadIdx.x;
  int bid = blockIdx.x;
  if (bid < 512) {
    int rowbase = bid * 64;
    float4 z4 = make_float4(0.f, 0.f, 0.f, 0.f);
    float4 acc[4] = {z4, z4, z4, z4};
    int r0 = (tid >> 4) << 2, c0 = (tid & 15) << 2;

    stage_W(Wt, sf_W, tid);
    stage_AT(At, river_upd + (size_t)(rowbase + (tid >> 2)) * 64, tid);
    __syncthreads();
    tile_gemm(At, Wt, acc, r0, c0);
    __syncthreads();

    stage_W(Wt, sf_W + 4096, tid);
    stage_AT(At, pooled + (size_t)(rowbase + (tid >> 2)) * 64, tid);
    __syncthreads();
    tile_gemm(At, Wt, acc, r0, c0);

    float4 b4 = *(const float4*)(sf_b + c0);
#pragma unroll
    for (int i = 0; i < 4; ++i) {
      float4 z;
      z.x = acc[i].x + b4.x; z.y = acc[i].y + b4.y;
      z.z = acc[i].z + b4.z; z.w = acc[i].w + b4.w;
      z.x = z.x / (1.f + expf(-z.x)); z.y = z.y / (1.f + expf(-z.y));
      z.z = z.z / (1.f + expf(-z.z)); z.w = z.w / (1.f + expf(-z.w));
      *(float4*)(x_spatial + (size_t)(rowbase + r0 + i) * 64 + c0) = z;
    }
  } else {
    // pfout: per-(b,n,f) LN over H + transpose to [H,T]
    float* l16 = At;                 // [16][65]
    float* mi = Wt; float* rs = Wt + 16;
    int bnf = bid - 512;
    int f = bnf & 7;
    int n = (bnf >> 3) & 1023;
    int b = bnf >> 13;
    for (int i = tid; i < 1024; i += 256) {
      int t = i >> 6, h = i & 63;
      l16[t * 65 + h] = cupd[(((size_t)b * TT + t) * NFD + n * FF + f) * HH + h];
    }
    __syncthreads();
    int t = tid >> 4, l = tid & 15;
    float sm = 0.f;
#pragma unroll
    for (int q = 0; q < 4; ++q) sm += l16[t * 65 + l + 16 * q];
    sm += __shfl_xor(sm, 1); sm += __shfl_xor(sm, 2); sm += __shfl_xor(sm, 4); sm += __shfl_xor(sm, 8);
    float m = sm * (1.f / 64.f);
    float sv = 0.f;
#pragma unroll
    for (int q = 0; q < 4; ++q) { float d = l16[t * 65 + l + 16 * q] - m; sv += d * d; }
    sv += __shfl_xor(sv, 1); sv += __shfl_xor(sv, 2); sv += __shfl_xor(sv, 4); sv += __shfl_xor(sv, 8);
    float inv = 1.f / sqrtf(sv * (1.f / 64.f) + 1e-5f);
    if (l == 0) { mi[t] = m; rs[t] = inv; }
    __syncthreads();
    float* out = pf_out + (size_t)bnf * (HH * TT);
    for (int i = tid; i < 1024; i += 256) {
      int h = i >> 4, tt = i & 15;
      out[i] = (l16[tt * 65 + h] - mi[tt]) * rs[tt] * g[h] + be[h];
    }
  }
}

// ---------------- fused tconv+f1 -> LN -> silu -> f2 -> out ----------------
__global__ __launch_bounds__(256, 4) void k_fuse2(const float* __restrict__ xt,
    const float* __restrict__ xsp, const float* __restrict__ Wg,
    const float* __restrict__ cvec, const float* __restrict__ f1W,
    const float* __restrict__ flng, const float* __restrict__ flnb,
    const float* __restrict__ f2W, const float* __restrict__ f2b,
    float* __restrict__ x_out) {
  __shared__ float At[64 * LDA];
  __shared__ float Wt[64 * LDA];
  int tid = threadIdx.x;
  int bn0 = blockIdx.x * 4;
  int srow = tid >> 2;
  int bnl = srow >> 4, t = srow & 15;
  int bn = bn0 + bnl;
  float4 z4 = make_float4(0.f, 0.f, 0.f, 0.f);
  float4 acc[4] = {z4, z4, z4, z4};
  int r0 = (tid >> 4) << 2, c0 = (tid & 15) << 2;

#pragma unroll
  for (int kt = 0; kt < 3; ++kt) {
    int t2 = t + kt - 1;
    const float* src = (t2 >= 0 && t2 < TT) ? xt + ((size_t)bn * TT + t2) * 64 : nullptr;
    stage_W(Wt, Wg + kt * 4096, tid);
    stage_AT(At, src, tid);
    __syncthreads();
    tile_gemm(At, Wt, acc, r0, c0);
    __syncthreads();
  }
  {
    int b = bn >> 10, n = bn & 1023;
    const float* src = xsp + ((size_t)(b * TT + t) * NN + n) * 64;
    stage_W(Wt, f1W + 4096, tid);
    stage_AT(At, src, tid);
    __syncthreads();
    tile_gemm(At, Wt, acc, r0, c0);
    __syncthreads();
  }

  float4 cv = *(const float4*)(cvec + c0);
  float4 g4 = *(const float4*)(flng + c0);
  float4 lb4 = *(const float4*)(flnb + c0);
  float4 zz[4];
#pragma unroll
  for (int i = 0; i < 4; ++i) {
    zz[i].x = acc[i].x + cv.x; zz[i].y = acc[i].y + cv.y;
    zz[i].z = acc[i].z + cv.z; zz[i].w = acc[i].w + cv.w;
    float ps = zz[i].x + zz[i].y + zz[i].z + zz[i].w;
    float pq = zz[i].x * zz[i].x + zz[i].y * zz[i].y + zz[i].z * zz[i].z + zz[i].w * zz[i].w;
    ps += __shfl_xor(ps, 1); pq += __shfl_xor(pq, 1);
    ps += __shfl_xor(ps, 2); pq += __shfl_xor(pq, 2);
    ps += __shfl_xor(ps, 4); pq += __shfl_xor(pq, 4);
    ps += __shfl_xor(ps, 8); pq += __shfl_xor(pq, 8);
    float m = ps * (1.f / 64.f);
    float var = pq * (1.f / 64.f) - m * m;
    float inv = rsqrtf(var + 1e-5f);
    float4 w;
    w.x = (zz[i].x - m) * inv * g4.x + lb4.x;
    w.y = (zz[i].y - m) * inv * g4.y + lb4.y;
    w.z = (zz[i].z - m) * inv * g4.z + lb4.z;
    w.w = (zz[i].w - m) * inv * g4.w + lb4.w;
    zz[i].x = w.x / (1.f + expf(-w.x));
    zz[i].y = w.y / (1.f + expf(-w.y));
    zz[i].z = w.z / (1.f + expf(-w.z));
    zz[i].w = w.w / (1.f + expf(-w.w));
  }
  {
    int xsw = ((c0 >> 4) & 3) << 2;
#pragma unroll
    for (int i = 0; i < 4; ++i) {
      int rr = (r0 + i) ^ xsw;
      At[(c0 + 0) * LDA + rr] = zz[i].x;
      At[(c0 + 1) * LDA + rr] = zz[i].y;
      At[(c0 + 2) * LDA + rr] = zz[i].z;
      At[(c0 + 3) * LDA + rr] = zz[i].w;
    }
  }
  stage_W(Wt, f2W, tid);
  __syncthreads();
  float4 acc2[4] = {z4, z4, z4, z4};
  tile_gemm(At, Wt, acc2, r0, c0);
  __syncthreads();
  float4 f2b4 = *(const float4*)(f2b + c0);
#pragma unroll
  for (int i = 0; i < 4; ++i) {
    float4 o;
    o.x = acc2[i].x + f2b4.x; o.y = acc2[i].y + f2b4.y;
    o.z = acc2[i].z + f2b4.z; o.w = acc2[i].w + f2b4.w;
    *(float4*)(Wt + (r0 + i) * LDA + c0) = o;
  }
  __syncthreads();
#pragma unroll
  for (int q = 0; q < 4; ++q) {
    int idx = tid + q * 256;
    int fo = idx * 4;
    int bnl2 = fo >> 10, rem = fo & 1023;
    int c = rem >> 4, tt = rem & 15;
    float4 o;
    o.x = Wt[(bnl2 * 16 + tt + 0) * LDA + c];
    o.y = Wt[(bnl2 * 16 + tt + 1) * LDA + c];
    o.z = Wt[(bnl2 * 16 + tt + 2) * LDA + c];
    o.w = Wt[(bnl2 * 16 + tt + 3) * LDA + c];
    *(float4*)(x_out + (size_t)(bn0 + bnl2) * 1024 + rem) = o;
  }
}

// ---------------- merged prep: edges + counters-zero (blocks<128) + weight-fold (>=128) ----------------
// weight-fold: one WAVE per output row; lane j = column. a-scalar is wave-uniform.
__global__ void k_prep(const float* __restrict__ attr, const float* __restrict__ cw,
                       const float* __restrict__ reW, const float* __restrict__ reB,
                       const float* __restrict__ rgate, const float* __restrict__ cgate,
                       float* __restrict__ mw_r, float* __restrict__ mw_c,
                       int* __restrict__ rcnt, int* __restrict__ ccnt,
                       const float* __restrict__ r_lin_W, const float* __restrict__ r_upd_W,
                       const float* __restrict__ r_lin_b,
                       const float* __restrict__ c_lin_W, const float* __restrict__ c_upd_W,
                       const float* __restrict__ c_lin_b,
                       const float* __restrict__ W_tc, const float* __restrict__ b_tc,
                       const float* __restrict__ f1_W, const float* __restrict__ f1_b,
                       float* __restrict__ Wfr, float* __restrict__ v_r,
                       float* __restrict__ Wfc, float* __restrict__ v_c,
                       float* __restrict__ Wg, float* __restrict__ cvec) {
  int bid = blockIdx.x;
  int tid = threadIdx.x;
  if (bid < 128) {
    int i = bid * 256 + tid;
    if (i < EC) {
      float gg = 1.f / (1.f + expf(-cgate[0]));
      mw_c[i] = fminf(fmaxf(gg * cw[i], 0.f), 1.f);
    }
    if (i < ER) {
      float ew = reB[0];
#pragma unroll
      for (int a = 0; a < EA; ++a) ew += attr[i * EA + a] * reW[a];
      float gg = 1.f / (1.f + expf(-rgate[0]));
      mw_r[i] = fminf(fmaxf(gg * ew, 0.f), 1.f);
    }
    if (i < NN) rcnt[i] = 0;
    if (i < NFD) ccnt[i] = 0;
  } else {
    int r = (bid - 128) * 4 + (tid >> 6);
    int j = tid & 63;
    const float* abase = nullptr;
    const float* bmat = nullptr;
    float* dst = nullptr;
    int astride = 1;
    if (r < 64)        { abase = r_lin_W + r * 64; bmat = r_upd_W; dst = Wfr + r * 64; }
    else if (r < 128)  { int rr = r - 64; abase = c_lin_W + rr * 64; bmat = c_upd_W; dst = Wfc + rr * 64; }
    else if (r < 320)  { int rr = r - 128; int kk = rr >> 6, i2 = rr & 63;
                         abase = W_tc + i2 * 3 + kk; astride = 192; bmat = f1_W; dst = Wg + rr * 64; }
    else if (r == 320) { abase = r_lin_b; bmat = r_upd_W; dst = v_r; }
    else if (r == 321) { abase = c_lin_b; bmat = c_upd_W; dst = v_c; }
    else if (r == 322) { abase = b_tc; bmat = f1_W; dst = cvec; }
    if (dst) {
      float s = (r == 322) ? f1_b[j] : 0.f;
#pragma unroll 8
      for (int m = 0; m < 64; ++m) s += abase[m * astride] * bmat[m * 64 + j];
      dst[j] = s;
    }
  }
}

// ---------------- CSR build ----------------
__global__ void k_count(const int* __restrict__ ridx, const int* __restrict__ cidx,
                        int* __restrict__ rcnt, int* __restrict__ ccnt) {
  int e = blockIdx.x * 256 + threadIdx.x;
  if (e < ER) atomicAdd(&rcnt[ridx[ER + e]], 1);
  if (e < EC) atomicAdd(&ccnt[cidx[EC + e]], 1);
}

template <int ITEMS>
__device__ __forceinline__ void scan_impl(const int* __restrict__ cnt, int n,
                                          int* __restrict__ off, int* __restrict__ cur,
                                          int* sh) {
  int tid = threadIdx.x;
  int local[ITEMS];
  int s = 0;
  int base = tid * ITEMS;
#pragma unroll
  for (int j = 0; j < ITEMS; ++j) { local[j] = cnt[base + j]; s += local[j]; }
  sh[tid] = s;
  __syncthreads();
  for (int d = 1; d < 1024; d <<= 1) {
    int v = (tid >= d) ? sh[tid - d] : 0;
    __syncthreads();
    sh[tid] += v;
    __syncthreads();
  }
  int excl = tid ? sh[tid - 1] : 0;
#pragma unroll
  for (int j = 0; j < ITEMS; ++j) { off[base + j] = excl; cur[base + j] = excl; excl += local[j]; }
  if (tid == 1023) off[n] = excl;
}

__global__ __launch_bounds__(1024) void k_scan(const int* __restrict__ rcnt, int* __restrict__ roff,
                                               int* __restrict__ rcur,
                                               const int* __restrict__ ccnt, int* __restrict__ coff,
                                               int* __restrict__ ccur) {
  __shared__ int sh[1024];
  if (blockIdx.x == 0) scan_impl<1>(rcnt, NN, roff, rcur, sh);
  else                 scan_impl<8>(ccnt, NFD, coff, ccur, sh);
}

__global__ void k_fill(const int* __restrict__ ridx, const int* __restrict__ cidx,
                       const float* __restrict__ mw_r, const float* __restrict__ mw_c,
                       int* __restrict__ rcur, int* __restrict__ ccur,
                       int2* __restrict__ rpk, int2* __restrict__ cpk) {
  int e = blockIdx.x * 256 + threadIdx.x;
  if (e < ER) {
    int t = ridx[ER + e]; int p = atomicAdd(&rcur[t], 1);
    rpk[p] = make_int2(ridx[e], __float_as_int(mw_r[e]));
  }
  if (e < EC) {
    int t = cidx[EC + e]; int p = atomicAdd(&ccur[t], 1);
    cpk[p] = make_int2(cidx[e], __float_as_int(mw_c[e]));
  }
}

// ---------------- merged layout transforms: xpose (blocks<2048) + nodes ----------------
__global__ void k_trans(const float* __restrict__ xg, float* __restrict__ x_bt,
                        float* __restrict__ xt,
                        const float* __restrict__ pfx, const float* __restrict__ femb,
                        float* __restrict__ nodes) {
  __shared__ float lds[64][17];
  int bid = blockIdx.x;
  int tid = threadIdx.x;
  if (bid < 2048) {
    int bn = bid;
    int b = bn >> 10, n = bn & 1023;
    const float* src = xg + (size_t)bn * (HH * TT);
    for (int i = tid; i < 1024; i += 256) lds[i >> 4][i & 15] = src[i];
    __syncthreads();
    for (int i = tid; i < 1024; i += 256) {
      int t = i >> 6, h = i & 63;
      float v = lds[h][t];
      float div = expf(-(float)(h & ~1) * (9.210340371976184f / 64.f));
      float arg = (float)t * div;
      float pe = (h & 1) ? cosf(arg) : sinf(arg);
      xt[(size_t)bn * 1024 + i] = v + pe;
      x_bt[(((size_t)b * TT + t) * NN + n) * HH + h] = v;
    }
  } else {
    int bnf = bid - 2048;
    int f = bnf & 7;
    int n = (bnf >> 3) & 1023;
    int b = bnf >> 13;
    const float* src = pfx + (size_t)bnf * (HH * TT);
    for (int i = tid; i < 1024; i += 256) lds[i >> 4][i & 15] = src[i];
    __syncthreads();
    for (int i = tid; i < 1024; i += 256) {
      int t = i >> 6, h = i & 63;
      nodes[(((size_t)b * TT + t) * NFD + n * FF + f) * HH + h] = lds[h][t] + femb[f * HH + h];
    }
  }
}

// ---------------- launch ----------------
extern "C" void kernel_launch(void* const* d_in, const int* in_sizes, int n_in,
                              void* d_out, int out_size, void* d_ws, size_t ws_size,
                              hipStream_t stream) {
  (void)in_sizes; (void)n_in; (void)out_size; (void)ws_size;
  const float* x_global     = (const float*)d_in[0];
  const float* per_feature  = (const float*)d_in[1];
  const float* r_edge_attr  = (const float*)d_in[2];
  const float* c_edge_w     = (const float*)d_in[3];
  const float* W_tc         = (const float*)d_in[4];
  const float* b_tc         = (const float*)d_in[5];
  const float* r_lin_W      = (const float*)d_in[6];
  const float* r_lin_b      = (const float*)d_in[7];
  const float* r_upd_W      = (const float*)d_in[8];
  const float* r_upd_b      = (const float*)d_in[9];
  const float* r_edge_W     = (const float*)d_in[10];
  const float* r_edge_b     = (const float*)d_in[11];
  const float* r_gate       = (const float*)d_in[12];
  const float* c_lin_W      = (const float*)d_in[13];
  const float* c_lin_b      = (const float*)d_in[14];
  const float* c_upd_W      = (const float*)d_in[15];
  const float* c_upd_b      = (const float*)d_in[16];
  const float* c_gate       = (const float*)d_in[17];
  const float* sf_W         = (const float*)d_in[18];
  const float* sf_b         = (const float*)d_in[19];
  const float* femb         = (const float*)d_in[20];
  const float* pfn_g        = (const float*)d_in[21];
  const float* pfn_b        = (const float*)d_in[22];
  const float* f1_W         = (const float*)d_in[23];
  const float* f1_b         = (const float*)d_in[24];
  const float* fln_g        = (const float*)d_in[25];
  const float* fln_b        = (const float*)d_in[26];
  const float* f2_W         = (const float*)d_in[27];
  const float* f2_b         = (const float*)d_in[28];
  const int*   ridx         = (const int*)d_in[29];
  const int*   cidx         = (const int*)d_in[30];

  float* out_f = (float*)d_out;
  float* x_out  = out_f;
  float* pf_out = out_f + 2097152;

  const size_t BTNFH = (size_t)BTT * NFD * HH;
  const size_t BTNH  = (size_t)BTT * NN * HH;

  float* ws = (float*)d_ws;
  size_t o = 0;
  float* nodes      = ws + o; o += BTNFH;
  float* cupd       = ws + o; o += BTNFH;
  float* x_bt       = ws + o; o += BTNH;
  float* xt         = ws + o; o += BTNH;
  float* river_upd  = ws + o; o += BTNH;
  float* pooled     = ws + o; o += BTNH;
  float* x_spatial  = ws + o; o += BTNH;
  float* mw_r       = ws + o; o += ER;
  float* mw_c       = ws + o; o += EC;
  float* Wfr        = ws + o; o += 4096;
  float* v_r        = ws + o; o += 64;
  float* Wfc        = ws + o; o += 4096;
  float* v_c        = ws + o; o += 64;
  float* Wg         = ws + o; o += 192 * 64;
  float* cvec       = ws + o; o += 64;
  int2* rpk = (int2*)(ws + o);
  int2* cpk = rpk + ER;
  int* ib = (int*)(cpk + EC);
  size_t io = 0;
  int* rcnt    = ib + io; io += NN;
  int* roff    = ib + io; io += NN + 1;
  int* rcur    = ib + io; io += NN + 1;
  int* ccnt    = ib + io; io += NFD;
  int* coff    = ib + io; io += NFD + 1;
  int* ccur    = ib + io; io += NFD + 1;

  k_prep<<<209, 256, 0, stream>>>(r_edge_attr, c_edge_w, r_edge_W, r_edge_b,
                                  r_gate, c_gate, mw_r, mw_c, rcnt, ccnt,
                                  r_lin_W, r_upd_W, r_lin_b, c_lin_W, c_upd_W, c_lin_b,
                                  W_tc, b_tc, f1_W, f1_b,
                                  Wfr, v_r, Wfc, v_c, Wg, cvec);
  k_count<<<128, 256, 0, stream>>>(ridx, cidx, rcnt, ccnt);
  k_scan<<<2, 1024, 0, stream>>>(rcnt, roff, rcur, ccnt, coff, ccur);
  k_fill<<<128, 256, 0, stream>>>(ridx, cidx, mw_r, mw_c, rcur, ccur, rpk, cpk);
  k_trans<<<2048 + BB * NN * FF, 256, 0, stream>>>(x_global, x_bt, xt,
                                                   per_feature, femb, nodes);
  k_gnn<<<512 + BTT * 128, 256, 0, stream>>>(x_bt, nodes, roff, rpk, coff, cpk,
                                             Wfr, r_upd_W + 4096, v_r, r_upd_b,
                                             Wfc, c_upd_W + 4096, v_c, c_upd_b,
                                             river_upd, cupd, pooled);
  k_post<<<512 + BB * NN * FF, 256, 0, stream>>>(river_upd, pooled, sf_W, sf_b,
                                                 x_spatial, cupd, pfn_g, pfn_b, pf_out);
  k_fuse2<<<512, 256, 0, stream>>>(xt, x_spatial, Wg, cvec, f1_W, fln_g, fln_b,
                                   f2_W, f2_b, x_out);
}